// Round 3
// baseline (15976.891 us; speedup 1.0000x reference)
//
#include <hip/hip_runtime.h>
#include <hip/hip_bf16.h>
#include <stdint.h>

typedef __attribute__((ext_vector_type(8))) short bf16x8;
typedef __attribute__((ext_vector_type(4))) float f32x4;

#define NB   16
#define SEQ  512
#define DM   256
#define G4   1024
#define VOC  32000
#define TOK  (NB*SEQ)          // 8192 tokens

// ---------------- workspace layout (bytes) ----------------
#define OF_SC     0                                  // float[8]
#define OF_AMAX   64                                 // uint[8]
#define OF_CNT    128                                // int[1024]: cnt0[512], cnt1[512]
#define OF_KEMB   16384                              // bf16 codes [8192,256]
#define OF_KWIH0  (OF_KEMB  + TOK*DM*2)              // bf16 codes [1024,256]
#define OF_KFC    (OF_KWIH0 + G4*DM*2)               // bf16 codes [32000,256]
#define OF_WP0    (OF_KFC   + VOC*DM*2)              // packed whh0 A-frags (512KB)
#define OF_WP1    (OF_WP0   + 32768*16)              // packed wih1|whh1 A-frags (1MB)
#define OF_HB0H   (OF_WP1   + 65536*16)              // h0 plane1 bf16 [512][16][256]
#define OF_HB0M   (OF_HB0H  + SEQ*NB*DM*2)           // h0 plane2
#define OF_HB0L   (OF_HB0M  + SEQ*NB*DM*2)           // h0 plane3
#define OF_HB1M   (OF_HB0L  + SEQ*NB*DM*2)           // h1 plane2
#define OF_HB1L   (OF_HB1M  + SEQ*NB*DM*2)           // h1 plane3
#define OF_XG     (OF_HB1L  + SEQ*NB*DM*2)           // f32 [8192,1024] layer0 input gates
#define OF_HOUT   (OF_XG    + (size_t)TOK*G4*4)      // bf16 [8192,256] h1 plane1 / FC input
// total ~81.5 MB

__device__ __forceinline__ unsigned short bf16b(float f) {
  __hip_bfloat16 h = __float2bfloat16(f);
  return *reinterpret_cast<unsigned short*>(&h);
}
__device__ __forceinline__ float bf16f(short u) {
  return __uint_as_float(((unsigned)(unsigned short)u) << 16);
}
__device__ __forceinline__ float quant_k_val(float w, float s) {
  float k = rintf(w / s);                       // round-half-even == jnp.round
  return fminf(fmaxf(k, -8.f), 7.f);
}
__device__ __forceinline__ float sigf(float x) { return 1.f / (1.f + expf(-x)); }

__device__ __forceinline__ void gload_lds16(const void* g, void* l) {
  __builtin_amdgcn_global_load_lds(
      (const __attribute__((address_space(1))) void*)g,
      (__attribute__((address_space(3))) void*)l, 16, 0, 0);
}

__device__ __forceinline__ void poll_ge(int* p, int v) {
  int it = 0;
  while (__hip_atomic_load(p, __ATOMIC_ACQUIRE, __HIP_MEMORY_SCOPE_AGENT) < v) {
    __builtin_amdgcn_s_sleep(2);
    if (++it > (1 << 14)) break;   // bailout: wrong answer beats hang
  }
}

// ---------------- scale computation ----------------
__global__ void k_init(unsigned int* amax, int* cnt) {
  if (threadIdx.x < 8) amax[threadIdx.x] = 0u;
  cnt[threadIdx.x] = 0;            // 1024 threads: cnt0[512]+cnt1[512]
}

__global__ void k_absmax(const float* __restrict__ p, int n, unsigned int* amax) {
  float m = 0.f;
  for (int i = blockIdx.x * blockDim.x + threadIdx.x; i < n; i += gridDim.x * blockDim.x)
    m = fmaxf(m, fabsf(p[i]));
  #pragma unroll
  for (int off = 32; off > 0; off >>= 1)
    m = fmaxf(m, __shfl_down(m, off));
  if ((threadIdx.x & 63) == 0) atomicMax(amax, __float_as_uint(m));
}

__global__ void k_finalize(const unsigned int* __restrict__ amax, float* __restrict__ sc) {
  int i = threadIdx.x;
  if (i < 6)       sc[i] = fmaxf(__uint_as_float(amax[i]) / 7.0f, 1e-8f);
  else if (i == 6) sc[i] = 1.0f;
}

// ---------------- quantize kernels ----------------
__global__ void k_quant_kbf16(const float* __restrict__ src, ushort* __restrict__ dst,
                              int n4, const float* __restrict__ sc, int slot) {
  int i = blockIdx.x * blockDim.x + threadIdx.x;
  if (i >= n4) return;
  const float s = sc[slot];
  float4 w = ((const float4*)src)[i];
  ushort4 o;
  o.x = bf16b(quant_k_val(w.x, s));
  o.y = bf16b(quant_k_val(w.y, s));
  o.z = bf16b(quant_k_val(w.z, s));
  o.w = bf16b(quant_k_val(w.w, s));
  ((ushort4*)dst)[i] = o;
}

__global__ void k_gather(const int* __restrict__ x, const float* __restrict__ emb,
                         const float* __restrict__ sc, ushort* __restrict__ out) {
  int i = blockIdx.x * blockDim.x + threadIdx.x;
  if (i >= TOK * 64) return;
  int tok = i >> 6, d4 = i & 63;
  const float s = sc[0];
  int row = x[tok];
  float4 w = *(const float4*)(emb + (size_t)row * DM + d4 * 4);
  ushort4 o;
  o.x = bf16b(quant_k_val(w.x, s));
  o.y = bf16b(quant_k_val(w.y, s));
  o.z = bf16b(quant_k_val(w.z, s));
  o.w = bf16b(quant_k_val(w.w, s));
  ((ushort4*)out)[i] = o;
}

// pack whh0 codes into per-wave MFMA A-fragment order:
// q = ((n*4+wv)*8+ks)*64 + lane ; row = wv*256+n*16+(lane&15), k = ks*32+((lane>>4)&3)*8+e
__global__ void k_pack0(const float* __restrict__ w, ushort* __restrict__ wp,
                        const float* __restrict__ sc) {
  int q = blockIdx.x * blockDim.x + threadIdx.x;
  if (q >= 16 * 4 * 8 * 64) return;
  int l = q & 63, ks = (q >> 6) & 7, wv = (q >> 9) & 3, n = q >> 11;
  int row = wv * 256 + n * 16 + (l & 15);
  int kb = ks * 32 + ((l >> 4) & 3) * 8;
  const float s = sc[2];
  bf16x8 o;
  #pragma unroll
  for (int e = 0; e < 8; ++e)
    o[e] = (short)bf16b(quant_k_val(w[(size_t)row * 256 + kb + e], s));
  ((bf16x8*)wp)[q] = o;
}

// pack wih1 (ks<8, scale sc[3]) and whh1 (ks>=8, sc[4]); wihl = wih+1024*256 etc.
__global__ void k_pack1(const float* __restrict__ wihl, const float* __restrict__ whhl,
                        ushort* __restrict__ wp, const float* __restrict__ sc) {
  int q = blockIdx.x * blockDim.x + threadIdx.x;
  if (q >= 16 * 4 * 16 * 64) return;
  int l = q & 63, ks = (q >> 6) & 15, wv = (q >> 10) & 3, n = q >> 12;
  int row = wv * 256 + n * 16 + (l & 15);
  const float* src = (ks < 8) ? wihl : whhl;
  const float s = (ks < 8) ? sc[3] : sc[4];
  int kb = ((ks < 8) ? ks : (ks - 8)) * 32 + ((l >> 4) & 3) * 8;
  bf16x8 o;
  #pragma unroll
  for (int e = 0; e < 8; ++e)
    o[e] = (short)bf16b(quant_k_val(src[(size_t)row * 256 + kb + e], s));
  ((bf16x8*)wp)[q] = o;
}

// ---------------- 128x128 MFMA bf16 GEMM (validated R1/R2) ----------------
__global__ __launch_bounds__(256) void k_gemm(
    const ushort* __restrict__ A, const ushort* __restrict__ B,
    float* __restrict__ C, int M, int N,
    const float* __restrict__ s1, const float* __restrict__ s2,
    const float* __restrict__ bias1, const float* __restrict__ bias2)
{
  __shared__ alignas(16) ushort As[128 * 64];
  __shared__ alignas(16) ushort Bs[128 * 64];
  const int tid  = threadIdx.x;
  const int lane = tid & 63;
  const int wid  = tid >> 6;
  const size_t m0 = (size_t)blockIdx.x * 128;
  const size_t n0 = (size_t)blockIdx.y * 128;
  const int wm = (wid >> 1) * 64;
  const int wn = (wid & 1) * 64;
  const int r  = tid >> 3;
  const int c8 = (tid & 7) * 8;

  f32x4 acc[4][4];
  #pragma unroll
  for (int m = 0; m < 4; ++m)
    #pragma unroll
    for (int n = 0; n < 4; ++n) acc[m][n] = (f32x4){0.f, 0.f, 0.f, 0.f};

  for (int k0 = 0; k0 < DM; k0 += 64) {
    #pragma unroll
    for (int i = 0; i < 4; ++i) {
      gload_lds16(A + (m0 + i * 32 + r) * DM + k0 + c8, (char*)As + i * 4096 + wid * 1024);
      gload_lds16(B + (n0 + i * 32 + r) * DM + k0 + c8, (char*)Bs + i * 4096 + wid * 1024);
    }
    __syncthreads();
    #pragma unroll
    for (int kk = 0; kk < 2; ++kk) {
      const int ko = (kk * 32 + ((lane >> 4) << 3)) * 2;
      bf16x8 af[4], bfr[4];
      #pragma unroll
      for (int m = 0; m < 4; ++m)
        af[m] = *(const bf16x8*)((const char*)As + (wm + m * 16 + (lane & 15)) * 128 + ko);
      #pragma unroll
      for (int n = 0; n < 4; ++n)
        bfr[n] = *(const bf16x8*)((const char*)Bs + (wn + n * 16 + (lane & 15)) * 128 + ko);
      #pragma unroll
      for (int m = 0; m < 4; ++m)
        #pragma unroll
        for (int n = 0; n < 4; ++n)
          acc[m][n] = __builtin_amdgcn_mfma_f32_16x16x32_bf16(af[m], bfr[n], acc[m][n], 0, 0, 0);
    }
    __syncthreads();
  }

  const float alpha = s1[0] * s2[0];
  const int cl = lane & 15;
  const int rq = (lane >> 4) * 4;
  #pragma unroll
  for (int n = 0; n < 4; ++n) {
    const size_t col = n0 + wn + n * 16 + cl;
    float badd = 0.f;
    if (bias1) badd += bias1[col];
    if (bias2) badd += bias2[col];
    #pragma unroll
    for (int m = 0; m < 4; ++m) {
      const size_t rowb = m0 + wm + m * 16 + rq;
      #pragma unroll
      for (int q = 0; q < 4; ++q)
        C[(rowb + q) * (size_t)N + col] = acc[m][n][q] * alpha + badd;
    }
  }
}

// ---------------- MFMA LSTM recurrence, weights register-resident ----------------
// 32 active blocks (bid%8==0, XCD-colocated), 256 threads (4 waves).
// m = bid>>3: stage = m&1 (0: layer0 rec, 1: layer1 full), n = m>>1 (j-slice).
// Wave wv = gate (i,f,g,o); A-frags (int4 codes, exact bf16) held in VGPRs all 512 steps.
// h broadcast: 3 exact bf16 planes (h = p1+p2+p3) in global, all-to-all via cnt[t].
__global__ __launch_bounds__(256) void k_rec(
    const bf16x8* __restrict__ WP0, const bf16x8* __restrict__ WP1,
    const float* __restrict__ XG,
    ushort* __restrict__ HB0h, ushort* __restrict__ HB0m, ushort* __restrict__ HB0l,
    ushort* __restrict__ HB1m, ushort* __restrict__ HB1l,
    ushort* __restrict__ HOUT,
    int* __restrict__ cnt0, int* __restrict__ cnt1,
    const float* __restrict__ sc,
    const float* __restrict__ bih, const float* __restrict__ bhh)
{
  const int bid = blockIdx.x;
  if (bid & 7) return;
  const int m = bid >> 3;
  if (m >= 32) return;
  const int stage = m & 1, n = m >> 1;
  const int tid  = threadIdx.x;
  const int lane = tid & 63, wv = tid >> 6;
  const int bA = lane & 15, kg = (lane >> 4) & 3;   // MFMA frag coords (col=b, k-group)
  const int bj = tid & 15,  jj = tid >> 4;          // activation coords (b, j)
  __shared__ float Gl[4][16][16];

  const bf16x8* HB0hv = (const bf16x8*)HB0h;
  const bf16x8* HB0mv = (const bf16x8*)HB0m;
  const bf16x8* HB0lv = (const bf16x8*)HB0l;
  const bf16x8* HB1mv = (const bf16x8*)HB1m;
  const bf16x8* HB1lv = (const bf16x8*)HB1l;
  const bf16x8* HOUTv = (const bf16x8*)HOUT;

  if (stage == 0) {
    bf16x8 a0[8];
    #pragma unroll
    for (int ks = 0; ks < 8; ++ks) a0[ks] = WP0[((n * 4 + wv) * 8 + ks) * 64 + lane];
    const float s2 = sc[2];
    float c0 = 0.f;
    for (int t = 0; t < SEQ; ++t) {
      if (t > 0) poll_ge(&cnt0[t - 1], 16);
      const size_t tok = (size_t)bj * SEQ + t;
      const size_t xb = tok * G4 + n * 16 + jj;
      float xv0 = XG[xb];
      float xv1 = XG[xb + 256];
      float xv2 = XG[xb + 512];
      float xv3 = XG[xb + 768];
      f32x4 pA = {0.f,0.f,0.f,0.f}, pB = pA, pC = pA;
      if (t > 0) {
        const size_t hb = ((size_t)(t - 1) * 16 + bA) * 32 + kg;
        #pragma unroll
        for (int ks = 0; ks < 8; ++ks) {
          bf16x8 f1 = HB0hv[hb + ks * 4];
          bf16x8 f2 = HB0mv[hb + ks * 4];
          bf16x8 f3 = HB0lv[hb + ks * 4];
          pA = __builtin_amdgcn_mfma_f32_16x16x32_bf16(a0[ks], f1, pA, 0, 0, 0);
          pB = __builtin_amdgcn_mfma_f32_16x16x32_bf16(a0[ks], f2, pB, 0, 0, 0);
          pC = __builtin_amdgcn_mfma_f32_16x16x32_bf16(a0[ks], f3, pC, 0, 0, 0);
        }
      }
      f32x4 asum = pA + pB + pC;
      #pragma unroll
      for (int q = 0; q < 4; ++q) Gl[wv][kg * 4 + q][bA] = asum[q];
      __syncthreads();
      float g0 = xv0 + s2 * Gl[0][jj][bj];
      float g1 = xv1 + s2 * Gl[1][jj][bj];
      float g2 = xv2 + s2 * Gl[2][jj][bj];
      float g3 = xv3 + s2 * Gl[3][jj][bj];
      float i_ = sigf(g0), f_ = sigf(g1), gg = tanhf(g2), o_ = sigf(g3);
      c0 = f_ * c0 + i_ * gg;
      float h = o_ * tanhf(c0);
      unsigned short p1 = bf16b(h);
      float r1 = h - bf16f((short)p1);
      unsigned short p2 = bf16b(r1);
      float r2 = r1 - bf16f((short)p2);
      unsigned short p3 = bf16b(r2);
      const size_t ho = ((size_t)t * 16 + bj) * 256 + n * 16 + jj;
      HB0h[ho] = p1; HB0m[ho] = p2; HB0l[ho] = p3;
      __syncthreads();
      if (tid == 0)
        __hip_atomic_fetch_add(&cnt0[t], 1, __ATOMIC_RELEASE, __HIP_MEMORY_SCOPE_AGENT);
    }
  } else {
    bf16x8 a1[16];
    #pragma unroll
    for (int ks = 0; ks < 16; ++ks) a1[ks] = WP1[((n * 4 + wv) * 16 + ks) * 64 + lane];
    const float s3 = sc[3], s4 = sc[4];
    const int bx = 1024 + n * 16 + jj;
    float bi0 = bih[bx] + bhh[bx];
    float bi1 = bih[bx + 256] + bhh[bx + 256];
    float bi2 = bih[bx + 512] + bhh[bx + 512];
    float bi3 = bih[bx + 768] + bhh[bx + 768];
    float c1 = 0.f;
    for (int t = 0; t < SEQ; ++t) {
      poll_ge(&cnt0[t], 16);
      if (t > 0) poll_ge(&cnt1[t - 1], 16);
      f32x4 z = {0.f,0.f,0.f,0.f};
      f32x4 iA = z, iB = z, iC = z, hA = z, hB = z, hC = z;
      {
        const size_t hb = ((size_t)t * 16 + bA) * 32 + kg;
        #pragma unroll
        for (int ks = 0; ks < 8; ++ks) {
          bf16x8 f1 = HB0hv[hb + ks * 4];
          bf16x8 f2 = HB0mv[hb + ks * 4];
          bf16x8 f3 = HB0lv[hb + ks * 4];
          iA = __builtin_amdgcn_mfma_f32_16x16x32_bf16(a1[ks], f1, iA, 0, 0, 0);
          iB = __builtin_amdgcn_mfma_f32_16x16x32_bf16(a1[ks], f2, iB, 0, 0, 0);
          iC = __builtin_amdgcn_mfma_f32_16x16x32_bf16(a1[ks], f3, iC, 0, 0, 0);
        }
      }
      if (t > 0) {
        const size_t h1i = ((size_t)bA * 512 + (t - 1)) * 32 + kg;   // HOUT [tok][k]
        const size_t hml = ((size_t)(t - 1) * 16 + bA) * 32 + kg;    // HB1 [t][b][k]
        #pragma unroll
        for (int ks = 0; ks < 8; ++ks) {
          bf16x8 f1 = HOUTv[h1i + ks * 4];
          bf16x8 f2 = HB1mv[hml + ks * 4];
          bf16x8 f3 = HB1lv[hml + ks * 4];
          hA = __builtin_amdgcn_mfma_f32_16x16x32_bf16(a1[8 + ks], f1, hA, 0, 0, 0);
          hB = __builtin_amdgcn_mfma_f32_16x16x32_bf16(a1[8 + ks], f2, hB, 0, 0, 0);
          hC = __builtin_amdgcn_mfma_f32_16x16x32_bf16(a1[8 + ks], f3, hC, 0, 0, 0);
        }
      }
      f32x4 isum = iA + iB + iC;
      f32x4 hsum = hA + hB + hC;
      #pragma unroll
      for (int q = 0; q < 4; ++q)
        Gl[wv][kg * 4 + q][bA] = s3 * isum[q] + s4 * hsum[q];
      __syncthreads();
      float g0 = bi0 + Gl[0][jj][bj];
      float g1 = bi1 + Gl[1][jj][bj];
      float g2 = bi2 + Gl[2][jj][bj];
      float g3 = bi3 + Gl[3][jj][bj];
      float i_ = sigf(g0), f_ = sigf(g1), gg = tanhf(g2), o_ = sigf(g3);
      c1 = f_ * c1 + i_ * gg;
      float h = o_ * tanhf(c1);
      unsigned short p1 = bf16b(h);
      float r1 = h - bf16f((short)p1);
      unsigned short p2 = bf16b(r1);
      float r2 = r1 - bf16f((short)p2);
      unsigned short p3 = bf16b(r2);
      HOUT[((size_t)bj * 512 + t) * 256 + n * 16 + jj] = p1;
      const size_t ho = ((size_t)t * 16 + bj) * 256 + n * 16 + jj;
      HB1m[ho] = p2; HB1l[ho] = p3;
      __syncthreads();
      if (tid == 0)
        __hip_atomic_fetch_add(&cnt1[t], 1, __ATOMIC_RELEASE, __HIP_MEMORY_SCOPE_AGENT);
    }
  }
}

// ---------------- launch ----------------
extern "C" void kernel_launch(void* const* d_in, const int* in_sizes, int n_in,
                              void* d_out, int out_size, void* d_ws, size_t ws_size,
                              hipStream_t stream) {
  const int*   x   = (const int*)d_in[0];
  const float* emb = (const float*)d_in[1];
  const float* wih = (const float*)d_in[2];   // [2,1024,256]
  const float* bih = (const float*)d_in[3];   // [2,1024]
  const float* whh = (const float*)d_in[4];
  const float* bhh = (const float*)d_in[5];
  const float* fcw = (const float*)d_in[6];   // [32000,256]
  const float* fcb = (const float*)d_in[7];
  float* out = (float*)d_out;

  char* ws = (char*)d_ws;
  float*        SC    = (float*)(ws + OF_SC);
  unsigned int* AMAX  = (unsigned int*)(ws + OF_AMAX);
  int*          CNT   = (int*)(ws + OF_CNT);
  ushort*       KEMB  = (ushort*)(ws + OF_KEMB);
  ushort*       KWIH0 = (ushort*)(ws + OF_KWIH0);
  ushort*       KFC   = (ushort*)(ws + OF_KFC);
  ushort*       WP0   = (ushort*)(ws + OF_WP0);
  ushort*       WP1   = (ushort*)(ws + OF_WP1);
  ushort*       HB0H  = (ushort*)(ws + OF_HB0H);
  ushort*       HB0M  = (ushort*)(ws + OF_HB0M);
  ushort*       HB0L  = (ushort*)(ws + OF_HB0L);
  ushort*       HB1M  = (ushort*)(ws + OF_HB1M);
  ushort*       HB1L  = (ushort*)(ws + OF_HB1L);
  float*        XG    = (float*)(ws + OF_XG);
  ushort*       HOUT  = (ushort*)(ws + OF_HOUT);

  const int nw = G4 * DM;

  k_init<<<1, 1024, 0, stream>>>(AMAX, CNT);
  k_absmax<<<2048, 256, 0, stream>>>(emb,      VOC * DM, AMAX + 0);
  k_absmax<<<256,  256, 0, stream>>>(wih,      nw,       AMAX + 1);
  k_absmax<<<256,  256, 0, stream>>>(whh,      nw,       AMAX + 2);
  k_absmax<<<256,  256, 0, stream>>>(wih + nw, nw,       AMAX + 3);
  k_absmax<<<256,  256, 0, stream>>>(whh + nw, nw,       AMAX + 4);
  k_absmax<<<2048, 256, 0, stream>>>(fcw,      VOC * DM, AMAX + 5);
  k_finalize<<<1, 8, 0, stream>>>(AMAX, SC);

  k_gather<<<TOK * 64 / 256, 256, 0, stream>>>(x, emb, SC, KEMB);
  k_quant_kbf16<<<nw / 4 / 256,       256, 0, stream>>>(wih, KWIH0, nw / 4,       SC, 1);
  k_quant_kbf16<<<VOC * DM / 4 / 256, 256, 0, stream>>>(fcw, KFC,   VOC * DM / 4, SC, 5);
  k_pack0<<<128, 256, 0, stream>>>(whh, WP0, SC);
  k_pack1<<<256, 256, 0, stream>>>(wih + nw, whh + nw, WP1, SC);

  // xgates(layer0) = s0*s1 * (k_emb @ k_wih0^T) + b_ih0 + b_hh0  (integer-exact MFMA)
  dim3 g1(TOK / 128, G4 / 128);
  k_gemm<<<g1, 256, 0, stream>>>(KEMB, KWIH0, XG, TOK, G4, SC + 0, SC + 1, bih, bhh);

  k_rec<<<256, 256, 0, stream>>>((const bf16x8*)WP0, (const bf16x8*)WP1, XG,
                                 HB0H, HB0M, HB0L, HB1M, HB1L, HOUT,
                                 CNT, CNT + 512, SC, bih, bhh);

  // logits = s_fc * (h @ k_fc^T) + fc_b
  dim3 g2(TOK / 128, VOC / 128);
  k_gemm<<<g2, 256, 0, stream>>>(HOUT, KFC, out, TOK, VOC, SC + 5, SC + 6, fcb, nullptr);
}

// Round 4
// 5387.131 us; speedup vs baseline: 2.9658x; 2.9658x over previous
//
#include <hip/hip_runtime.h>
#include <hip/hip_bf16.h>
#include <stdint.h>

typedef __attribute__((ext_vector_type(8))) short bf16x8;
typedef __attribute__((ext_vector_type(4))) float f32x4;

#define NB   16
#define SEQ  512
#define DM   256
#define G4   1024
#define VOC  32000
#define TOK  (NB*SEQ)          // 8192 tokens

// ---------------- workspace layout (bytes) ----------------
#define OF_SC     0                                  // float[8]
#define OF_AMAX   64                                 // uint[8]
#define OF_FLAG   128                                // int[24*32]: one flag per 128B line
#define OF_KEMB   16384                              // bf16 codes [8192,256]
#define OF_KWIH0  (OF_KEMB  + TOK*DM*2)              // bf16 codes [1024,256]
#define OF_KFC    (OF_KWIH0 + G4*DM*2)               // bf16 codes [32000,256]
#define OF_WL0    (OF_KFC   + VOC*DM*2)              // whh0 A-frags 512KB
#define OF_WFF    (OF_WL0   + 512*64*16)             // wih1 A-frags 512KB
#define OF_WL1    (OF_WFF   + 512*64*16)             // whh1 A-frags 512KB
#define OF_XG1    (OF_WL1   + 512*64*16)             // f32 [2][1024][16] xg1 double-buffer
#define OF_HX0    (OF_XG1   + 2*G4*16*4)             // h0 frags [2][8kf][3p][64l][8e] bf16 (48KB)
#define OF_HX1    (OF_HX0   + 2*1536*16)             // h1 frags same (48KB)
#define OF_XG     (OF_HX1   + 2*1536*16)             // f32 [8192,1024] layer0 input gates
#define OF_HOUT   (OF_XG    + (size_t)TOK*G4*4)      // bf16 [8192,256] h1 (FC input)
// total ~61 MB

__device__ __forceinline__ unsigned short bf16b(float f) {
  __hip_bfloat16 h = __float2bfloat16(f);
  return *reinterpret_cast<unsigned short*>(&h);
}
__device__ __forceinline__ float bf16f(short u) {
  return __uint_as_float(((unsigned)(unsigned short)u) << 16);
}
__device__ __forceinline__ float quant_k_val(float w, float s) {
  float k = rintf(w / s);                       // round-half-even == jnp.round
  return fminf(fmaxf(k, -8.f), 7.f);
}
__device__ __forceinline__ float sigf(float x) { return 1.f / (1.f + expf(-x)); }

__device__ __forceinline__ void gload_lds16(const void* g, void* l) {
  __builtin_amdgcn_global_load_lds(
      (const __attribute__((address_space(1))) void*)g,
      (__attribute__((address_space(3))) void*)l, 16, 0, 0);
}

// single-writer flag on its own 128B line; per-lane spin (divergent loop is fine)
__device__ __forceinline__ void spin_ge(int* p, int tgt) {
  int it = 0;
  while (__hip_atomic_load(p, __ATOMIC_ACQUIRE, __HIP_MEMORY_SCOPE_AGENT) < tgt) {
    __builtin_amdgcn_s_sleep(1);
    if (++it > (1 << 15)) break;   // bailout: wrong answer beats hang
  }
}

// ---------------- scale computation ----------------
__global__ void k_init(unsigned int* amax, int* flags) {
  if (threadIdx.x < 8) amax[threadIdx.x] = 0u;
  if (threadIdx.x < 24 * 32) flags[threadIdx.x] = 0;
}

__global__ void k_absmax(const float* __restrict__ p, int n, unsigned int* amax) {
  float m = 0.f;
  for (int i = blockIdx.x * blockDim.x + threadIdx.x; i < n; i += gridDim.x * blockDim.x)
    m = fmaxf(m, fabsf(p[i]));
  #pragma unroll
  for (int off = 32; off > 0; off >>= 1)
    m = fmaxf(m, __shfl_down(m, off));
  if ((threadIdx.x & 63) == 0) atomicMax(amax, __float_as_uint(m));
}

__global__ void k_finalize(const unsigned int* __restrict__ amax, float* __restrict__ sc) {
  int i = threadIdx.x;
  if (i < 6)       sc[i] = fmaxf(__uint_as_float(amax[i]) / 7.0f, 1e-8f);
  else if (i == 6) sc[i] = 1.0f;
}

// ---------------- quantize kernels ----------------
__global__ void k_quant_kbf16(const float* __restrict__ src, ushort* __restrict__ dst,
                              int n4, const float* __restrict__ sc, int slot) {
  int i = blockIdx.x * blockDim.x + threadIdx.x;
  if (i >= n4) return;
  const float s = sc[slot];
  float4 w = ((const float4*)src)[i];
  ushort4 o;
  o.x = bf16b(quant_k_val(w.x, s));
  o.y = bf16b(quant_k_val(w.y, s));
  o.z = bf16b(quant_k_val(w.z, s));
  o.w = bf16b(quant_k_val(w.w, s));
  ((ushort4*)dst)[i] = o;
}

__global__ void k_gather(const int* __restrict__ x, const float* __restrict__ emb,
                         const float* __restrict__ sc, ushort* __restrict__ out) {
  int i = blockIdx.x * blockDim.x + threadIdx.x;
  if (i >= TOK * 64) return;
  int tok = i >> 6, d4 = i & 63;
  const float s = sc[0];
  int row = x[tok];
  float4 w = *(const float4*)(emb + (size_t)row * DM + d4 * 4);
  ushort4 o;
  o.x = bf16b(quant_k_val(w.x, s));
  o.y = bf16b(quant_k_val(w.y, s));
  o.z = bf16b(quant_k_val(w.z, s));
  o.w = bf16b(quant_k_val(w.w, s));
  ((ushort4*)out)[i] = o;
}

// pack A-frags: frag fi = ((g*4+w)*2+i)*8+kf, lane l.
// mode 0 (L0/L1): row = w*256 + g*32 + i*16 + (l&15)   (wave = gate)
// mode 1 (FF):    row = g*128 + (w*2+i)*16 + (l&15)
// k = kf*32 + ((l>>4)&3)*8 + e   (validated A-frag layout, R3)
__global__ void k_packrec(const float* __restrict__ src, bf16x8* __restrict__ dst,
                          const float* __restrict__ sc, int slot, int mode) {
  int q = blockIdx.x * blockDim.x + threadIdx.x;
  if (q >= 512 * 64) return;
  int l = q & 63, kf = (q >> 6) & 7, i = (q >> 9) & 1, w = (q >> 10) & 3, g = (q >> 12) & 7;
  int row = mode ? (g * 128 + (w * 2 + i) * 16 + (l & 15))
                 : (w * 256 + g * 32 + i * 16 + (l & 15));
  int kb = kf * 32 + ((l >> 4) & 3) * 8;
  const float s = sc[slot];
  const float* p = src + (size_t)row * DM + kb;
  bf16x8 o;
  #pragma unroll
  for (int e = 0; e < 8; ++e) o[e] = (short)bf16b(quant_k_val(p[e], s));
  dst[q] = o;
}

// ---------------- 128x128 MFMA bf16 GEMM (validated R1-R3) ----------------
__global__ __launch_bounds__(256) void k_gemm(
    const ushort* __restrict__ A, const ushort* __restrict__ B,
    float* __restrict__ C, int M, int N,
    const float* __restrict__ s1, const float* __restrict__ s2,
    const float* __restrict__ bias1, const float* __restrict__ bias2)
{
  __shared__ alignas(16) ushort As[128 * 64];
  __shared__ alignas(16) ushort Bs[128 * 64];
  const int tid  = threadIdx.x;
  const int lane = tid & 63;
  const int wid  = tid >> 6;
  const size_t m0 = (size_t)blockIdx.x * 128;
  const size_t n0 = (size_t)blockIdx.y * 128;
  const int wm = (wid >> 1) * 64;
  const int wn = (wid & 1) * 64;
  const int r  = tid >> 3;
  const int c8 = (tid & 7) * 8;

  f32x4 acc[4][4];
  #pragma unroll
  for (int m = 0; m < 4; ++m)
    #pragma unroll
    for (int n = 0; n < 4; ++n) acc[m][n] = (f32x4){0.f, 0.f, 0.f, 0.f};

  for (int k0 = 0; k0 < DM; k0 += 64) {
    #pragma unroll
    for (int i = 0; i < 4; ++i) {
      gload_lds16(A + (m0 + i * 32 + r) * DM + k0 + c8, (char*)As + i * 4096 + wid * 1024);
      gload_lds16(B + (n0 + i * 32 + r) * DM + k0 + c8, (char*)Bs + i * 4096 + wid * 1024);
    }
    __syncthreads();
    #pragma unroll
    for (int kk = 0; kk < 2; ++kk) {
      const int ko = (kk * 32 + ((lane >> 4) << 3)) * 2;
      bf16x8 af[4], bfr[4];
      #pragma unroll
      for (int m = 0; m < 4; ++m)
        af[m] = *(const bf16x8*)((const char*)As + (wm + m * 16 + (lane & 15)) * 128 + ko);
      #pragma unroll
      for (int n = 0; n < 4; ++n)
        bfr[n] = *(const bf16x8*)((const char*)Bs + (wn + n * 16 + (lane & 15)) * 128 + ko);
      #pragma unroll
      for (int m = 0; m < 4; ++m)
        #pragma unroll
        for (int n = 0; n < 4; ++n)
          acc[m][n] = __builtin_amdgcn_mfma_f32_16x16x32_bf16(af[m], bfr[n], acc[m][n], 0, 0, 0);
    }
    __syncthreads();
  }

  const float alpha = s1[0] * s2[0];
  const int cl = lane & 15;
  const int rq = (lane >> 4) * 4;
  #pragma unroll
  for (int n = 0; n < 4; ++n) {
    const size_t col = n0 + wn + n * 16 + cl;
    float badd = 0.f;
    if (bias1) badd += bias1[col];
    if (bias2) badd += bias2[col];
    #pragma unroll
    for (int m = 0; m < 4; ++m) {
      const size_t rowb = m0 + wm + m * 16 + rq;
      #pragma unroll
      for (int q = 0; q < 4; ++q)
        C[(rowb + q) * (size_t)N + col] = acc[m][n][q] * alpha + badd;
    }
  }
}

// ---------------- register-resident MFMA LSTM, 24-block wavefront pipeline ----------------
// Active blocks: bid%8==0 (XCD-colocated), m=bid>>3: m<8 L0[g], m<16 FF[g], m<24 L1[g].
// Each block: 256 threads (4 waves; wave = gate for L0/L1), owns 32 h-rows = frag kf g.
// Flags: flags[line*32], line 0..7 L0, 8..15 FF, 16..23 L1 (single writer each).
// h exchanged as 3 exact bf16 planes in B-frag layout (1KB contiguous per frag), dbuf t&1.
__global__ __launch_bounds__(256) void k_rec2(
    const bf16x8* __restrict__ WL0, const bf16x8* __restrict__ WFF,
    const bf16x8* __restrict__ WL1,
    const float* __restrict__ XG, float* __restrict__ XG1,
    ushort* __restrict__ HX0, ushort* __restrict__ HX1,
    ushort* __restrict__ HOUT, int* __restrict__ flags,
    const float* __restrict__ sc,
    const float* __restrict__ bih, const float* __restrict__ bhh)
{
  if (blockIdx.x & 7) return;
  const int m = blockIdx.x >> 3;
  if (m >= 24) return;
  const int role = m >> 3;          // 0 L0, 1 FF, 2 L1
  const int g = m & 7;
  const int tid = threadIdx.x, lane = tid & 63, w = tid >> 6;
  const int kg = lane >> 4, cb = lane & 15;
  const int r0 = tid & 31, b0 = tid >> 5;

  __shared__ alignas(16) ushort Bs[24 * 512];   // 24 B-frags (8kf x 3planes), 24KB
  __shared__ float Gl[4 * 32 * 17];             // gates [gate][32 rows][pad17]

  // resident A-frags: a[i*8+kf] for the wave's two 16-row tiles
  bf16x8 a[16];
  const bf16x8* WP = (role == 0) ? WL0 : (role == 1 ? WFF : WL1);
  #pragma unroll
  for (int i = 0; i < 2; ++i)
    #pragma unroll
    for (int kf = 0; kf < 8; ++kf)
      a[i * 8 + kf] = WP[((((g * 4 + w) * 2 + i) * 8 + kf) << 6) + lane];

  if (role == 0) {
    // ================= layer-0 recurrence =================
    const float s2 = sc[2];
    float cc[2] = {0.f, 0.f};
    for (int t = 0; t < SEQ; ++t) {
      // prefetch xg (static data, hidden under poll+stage+mfma)
      float xv[2][4];
      #pragma unroll
      for (int i = 0; i < 2; ++i)
        #pragma unroll
        for (int gt = 0; gt < 4; ++gt)
          xv[i][gt] = XG[(size_t)((b0 + i * 8) * 512 + t) * G4 + gt * 256 + g * 32 + r0];
      // poll: peers >= t (h0[t-1]); FF consumers >= t-1 (slot free)
      if (tid < 16) spin_ge(flags + tid * 32, (tid < 8) ? t : t - 1);
      __syncthreads();
      if (t > 0) {
        const int sl = (t - 1) & 1;
        #pragma unroll
        for (int c = 0; c < 6; ++c)
          gload_lds16(HX0 + ((size_t)sl * 1536 + c * 256 + tid) * 8,
                      (char*)Bs + (c * 256 + (tid & 192)) * 16);
      }
      __syncthreads();
      f32x4 acc0 = {0.f,0.f,0.f,0.f}, acc1 = {0.f,0.f,0.f,0.f};
      if (t > 0) {
        #pragma unroll
        for (int kf = 0; kf < 8; ++kf)
          #pragma unroll
          for (int p = 0; p < 3; ++p) {
            bf16x8 bf = *(const bf16x8*)(Bs + (kf * 3 + p) * 512 + lane * 8);
            acc0 = __builtin_amdgcn_mfma_f32_16x16x32_bf16(a[kf],     bf, acc0, 0, 0, 0);
            acc1 = __builtin_amdgcn_mfma_f32_16x16x32_bf16(a[8 + kf], bf, acc1, 0, 0, 0);
          }
      }
      #pragma unroll
      for (int q = 0; q < 4; ++q) {
        Gl[(w * 32      + kg * 4 + q) * 17 + cb] = acc0[q];
        Gl[(w * 32 + 16 + kg * 4 + q) * 17 + cb] = acc1[q];
      }
      __syncthreads();
      const int sl = t & 1;
      #pragma unroll
      for (int i = 0; i < 2; ++i) {
        const int b = b0 + i * 8;
        float g0 = xv[i][0] + s2 * Gl[(0 * 32 + r0) * 17 + b];
        float g1 = xv[i][1] + s2 * Gl[(1 * 32 + r0) * 17 + b];
        float g2 = xv[i][2] + s2 * Gl[(2 * 32 + r0) * 17 + b];
        float g3 = xv[i][3] + s2 * Gl[(3 * 32 + r0) * 17 + b];
        float i_ = sigf(g0), f_ = sigf(g1), gg = tanhf(g2), o_ = sigf(g3);
        cc[i] = f_ * cc[i] + i_ * gg;
        float h = o_ * tanhf(cc[i]);
        unsigned short p1 = bf16b(h);
        float r1 = h - bf16f((short)p1);
        unsigned short p2 = bf16b(r1);
        float r2 = r1 - bf16f((short)p2);
        unsigned short p3 = bf16b(r2);
        const int l2 = ((r0 >> 3) << 4) | b;
        const size_t base = ((size_t)sl * 24 + g * 3) * 512 + l2 * 8 + (r0 & 7);
        HX0[base] = p1; HX0[base + 512] = p2; HX0[base + 1024] = p3;
      }
      __syncthreads();   // drains every thread's stores, then barrier
      if (tid == 0)
        __hip_atomic_store(flags + g * 32, t + 1, __ATOMIC_RELEASE, __HIP_MEMORY_SCOPE_AGENT);
    }
  } else if (role == 1) {
    // ================= feed-forward xg1 = s3*(wih1.h0[t]) + bias =================
    const float s3 = sc[3];
    float br[2][4];
    #pragma unroll
    for (int i = 0; i < 2; ++i)
      #pragma unroll
      for (int q = 0; q < 4; ++q) {
        int j = g * 128 + (w * 2 + i) * 16 + kg * 4 + q;
        br[i][q] = bih[G4 + j] + bhh[G4 + j];
      }
    for (int t = 0; t < SEQ; ++t) {
      // poll: L0 >= t+1 (h0[t]); L1 >= t-1 (xg1 slot free)
      if (tid < 16) spin_ge(flags + ((tid < 8) ? tid : tid + 8) * 32, (tid < 8) ? t + 1 : t - 1);
      __syncthreads();
      const int sl = t & 1;
      #pragma unroll
      for (int c = 0; c < 6; ++c)
        gload_lds16(HX0 + ((size_t)sl * 1536 + c * 256 + tid) * 8,
                    (char*)Bs + (c * 256 + (tid & 192)) * 16);
      __syncthreads();
      f32x4 acc0 = {0.f,0.f,0.f,0.f}, acc1 = {0.f,0.f,0.f,0.f};
      #pragma unroll
      for (int kf = 0; kf < 8; ++kf)
        #pragma unroll
        for (int p = 0; p < 3; ++p) {
          bf16x8 bf = *(const bf16x8*)(Bs + (kf * 3 + p) * 512 + lane * 8);
          acc0 = __builtin_amdgcn_mfma_f32_16x16x32_bf16(a[kf],     bf, acc0, 0, 0, 0);
          acc1 = __builtin_amdgcn_mfma_f32_16x16x32_bf16(a[8 + kf], bf, acc1, 0, 0, 0);
        }
      #pragma unroll
      for (int i = 0; i < 2; ++i)
        #pragma unroll
        for (int q = 0; q < 4; ++q) {
          int j = g * 128 + (w * 2 + i) * 16 + kg * 4 + q;
          float v = (i ? acc1[q] : acc0[q]) * s3 + br[i][q];
          XG1[(size_t)(sl * G4 + j) * 16 + cb] = v;
        }
      __syncthreads();
      if (tid == 0)
        __hip_atomic_store(flags + (8 + g) * 32, t + 1, __ATOMIC_RELEASE, __HIP_MEMORY_SCOPE_AGENT);
    }
  } else {
    // ================= layer-1 recurrence =================
    const float s4 = sc[4];
    float cc[2] = {0.f, 0.f};
    for (int t = 0; t < SEQ; ++t) {
      // poll: FF >= t+1 (xg1[t]); peers >= t (h1[t-1])
      if (tid < 16) spin_ge(flags + (8 + tid) * 32, (tid < 8) ? t + 1 : t);
      __syncthreads();
      // xg1 loads (valid after FF flag)
      float xv[2][4];
      #pragma unroll
      for (int i = 0; i < 2; ++i)
        #pragma unroll
        for (int gt = 0; gt < 4; ++gt)
          xv[i][gt] = XG1[(size_t)((t & 1) * G4 + gt * 256 + g * 32 + r0) * 16 + b0 + i * 8];
      if (t > 0) {
        const int sl = (t - 1) & 1;
        #pragma unroll
        for (int c = 0; c < 6; ++c)
          gload_lds16(HX1 + ((size_t)sl * 1536 + c * 256 + tid) * 8,
                      (char*)Bs + (c * 256 + (tid & 192)) * 16);
      }
      __syncthreads();
      f32x4 acc0 = {0.f,0.f,0.f,0.f}, acc1 = {0.f,0.f,0.f,0.f};
      if (t > 0) {
        #pragma unroll
        for (int kf = 0; kf < 8; ++kf)
          #pragma unroll
          for (int p = 0; p < 3; ++p) {
            bf16x8 bf = *(const bf16x8*)(Bs + (kf * 3 + p) * 512 + lane * 8);
            acc0 = __builtin_amdgcn_mfma_f32_16x16x32_bf16(a[kf],     bf, acc0, 0, 0, 0);
            acc1 = __builtin_amdgcn_mfma_f32_16x16x32_bf16(a[8 + kf], bf, acc1, 0, 0, 0);
          }
      }
      #pragma unroll
      for (int q = 0; q < 4; ++q) {
        Gl[(w * 32      + kg * 4 + q) * 17 + cb] = acc0[q];
        Gl[(w * 32 + 16 + kg * 4 + q) * 17 + cb] = acc1[q];
      }
      __syncthreads();
      const int sl = t & 1;
      #pragma unroll
      for (int i = 0; i < 2; ++i) {
        const int b = b0 + i * 8;
        float g0 = xv[i][0] + s4 * Gl[(0 * 32 + r0) * 17 + b];
        float g1 = xv[i][1] + s4 * Gl[(1 * 32 + r0) * 17 + b];
        float g2 = xv[i][2] + s4 * Gl[(2 * 32 + r0) * 17 + b];
        float g3 = xv[i][3] + s4 * Gl[(3 * 32 + r0) * 17 + b];
        float i_ = sigf(g0), f_ = sigf(g1), gg = tanhf(g2), o_ = sigf(g3);
        cc[i] = f_ * cc[i] + i_ * gg;
        float h = o_ * tanhf(cc[i]);
        unsigned short p1 = bf16b(h);
        float r1 = h - bf16f((short)p1);
        unsigned short p2 = bf16b(r1);
        float r2 = r1 - bf16f((short)p2);
        unsigned short p3 = bf16b(r2);
        HOUT[(size_t)(b * 512 + t) * 256 + g * 32 + r0] = p1;
        const int l2 = ((r0 >> 3) << 4) | b;
        const size_t base = ((size_t)sl * 24 + g * 3) * 512 + l2 * 8 + (r0 & 7);
        HX1[base] = p1; HX1[base + 512] = p2; HX1[base + 1024] = p3;
      }
      __syncthreads();
      if (tid == 0)
        __hip_atomic_store(flags + (16 + g) * 32, t + 1, __ATOMIC_RELEASE, __HIP_MEMORY_SCOPE_AGENT);
    }
  }
}

// ---------------- launch ----------------
extern "C" void kernel_launch(void* const* d_in, const int* in_sizes, int n_in,
                              void* d_out, int out_size, void* d_ws, size_t ws_size,
                              hipStream_t stream) {
  const int*   x   = (const int*)d_in[0];
  const float* emb = (const float*)d_in[1];
  const float* wih = (const float*)d_in[2];   // [2,1024,256]
  const float* bih = (const float*)d_in[3];   // [2,1024]
  const float* whh = (const float*)d_in[4];
  const float* bhh = (const float*)d_in[5];
  const float* fcw = (const float*)d_in[6];   // [32000,256]
  const float* fcb = (const float*)d_in[7];
  float* out = (float*)d_out;

  char* ws = (char*)d_ws;
  float*        SC    = (float*)(ws + OF_SC);
  unsigned int* AMAX  = (unsigned int*)(ws + OF_AMAX);
  int*          FLAGS = (int*)(ws + OF_FLAG);
  ushort*       KEMB  = (ushort*)(ws + OF_KEMB);
  ushort*       KWIH0 = (ushort*)(ws + OF_KWIH0);
  ushort*       KFC   = (ushort*)(ws + OF_KFC);
  bf16x8*       WL0   = (bf16x8*)(ws + OF_WL0);
  bf16x8*       WFF   = (bf16x8*)(ws + OF_WFF);
  bf16x8*       WL1   = (bf16x8*)(ws + OF_WL1);
  float*        XG1   = (float*)(ws + OF_XG1);
  ushort*       HX0   = (ushort*)(ws + OF_HX0);
  ushort*       HX1   = (ushort*)(ws + OF_HX1);
  float*        XG    = (float*)(ws + OF_XG);
  ushort*       HOUT  = (ushort*)(ws + OF_HOUT);

  const int nw = G4 * DM;

  k_init<<<1, 1024, 0, stream>>>(AMAX, FLAGS);
  k_absmax<<<2048, 256, 0, stream>>>(emb,      VOC * DM, AMAX + 0);
  k_absmax<<<256,  256, 0, stream>>>(wih,      nw,       AMAX + 1);
  k_absmax<<<256,  256, 0, stream>>>(whh,      nw,       AMAX + 2);
  k_absmax<<<256,  256, 0, stream>>>(wih + nw, nw,       AMAX + 3);
  k_absmax<<<256,  256, 0, stream>>>(whh + nw, nw,       AMAX + 4);
  k_absmax<<<2048, 256, 0, stream>>>(fcw,      VOC * DM, AMAX + 5);
  k_finalize<<<1, 8, 0, stream>>>(AMAX, SC);

  k_gather<<<TOK * 64 / 256, 256, 0, stream>>>(x, emb, SC, KEMB);
  k_quant_kbf16<<<nw / 4 / 256,       256, 0, stream>>>(wih, KWIH0, nw / 4,       SC, 1);
  k_quant_kbf16<<<VOC * DM / 4 / 256, 256, 0, stream>>>(fcw, KFC,   VOC * DM / 4, SC, 5);
  k_packrec<<<128, 256, 0, stream>>>(whh,      WL0, SC, 2, 0);
  k_packrec<<<128, 256, 0, stream>>>(wih + nw, WFF, SC, 3, 1);
  k_packrec<<<128, 256, 0, stream>>>(whh + nw, WL1, SC, 4, 0);

  // xgates(layer0) = s0*s1 * (k_emb @ k_wih0^T) + b_ih0 + b_hh0  (integer-exact MFMA)
  dim3 g1(TOK / 128, G4 / 128);
  k_gemm<<<g1, 256, 0, stream>>>(KEMB, KWIH0, XG, TOK, G4, SC + 0, SC + 1, bih, bhh);

  k_rec2<<<192, 256, 0, stream>>>(WL0, WFF, WL1, XG, XG1, HX0, HX1, HOUT,
                                  FLAGS, SC, bih, bhh);

  // logits = s_fc * (h @ k_fc^T) + fc_b
  dim3 g2(TOK / 128, VOC / 128);
  k_gemm<<<g2, 256, 0, stream>>>(HOUT, KFC, out, TOK, VOC, SC + 5, SC + 6, fcb, nullptr);
}

// Round 5
// 2872.587 us; speedup vs baseline: 5.5618x; 1.8754x over previous
//
#include <hip/hip_runtime.h>
#include <hip/hip_bf16.h>
#include <stdint.h>

typedef __attribute__((ext_vector_type(8))) short bf16x8;
typedef __attribute__((ext_vector_type(4))) float f32x4;

#define NB   16
#define SEQ  512
#define DM   256
#define G4   1024
#define VOC  32000
#define TOK  (NB*SEQ)          // 8192 tokens

// ---------------- workspace layout (bytes) ----------------
#define OF_SC     0                                  // float[8]
#define OF_AMAX   64                                 // uint[8]
#define OF_FLAG   128                                // int[24*32]: one flag per 128B line
#define OF_KEMB   16384                              // bf16 codes [8192,256]
#define OF_KWIH0  (OF_KEMB  + TOK*DM*2)              // bf16 codes [1024,256]
#define OF_KFC    (OF_KWIH0 + G4*DM*2)               // bf16 codes [32000,256]
#define OF_WL0    (OF_KFC   + VOC*DM*2)              // whh0 A-frags 512KB
#define OF_WFF    (OF_WL0   + 512*64*16)             // wih1 A-frags 512KB
#define OF_WL1    (OF_WFF   + 512*64*16)             // whh1 A-frags 512KB
#define OF_XG1    (OF_WL1   + 512*64*16)             // f32 [4 slots][1024][16] xg1
#define OF_HX0    (OF_XG1   + 4*G4*16*4)             // h0 frags [4 slots][24 frag][1KB]
#define OF_HX1    (OF_HX0   + 4*24576)               // h1 frags same
#define OF_XG     (OF_HX1   + 4*24576)               // f32 [8192,1024] layer0 input gates
#define OF_HOUT   (OF_XG    + (size_t)TOK*G4*4)      // bf16 [8192,256] h1 (FC input)

__device__ __forceinline__ unsigned short bf16b(float f) {
  __hip_bfloat16 h = __float2bfloat16(f);
  return *reinterpret_cast<unsigned short*>(&h);
}
__device__ __forceinline__ float bf16f(short u) {
  return __uint_as_float(((unsigned)(unsigned short)u) << 16);
}
__device__ __forceinline__ float quant_k_val(float w, float s) {
  float k = rintf(w / s);                       // round-half-even == jnp.round
  return fminf(fmaxf(k, -8.f), 7.f);
}
__device__ __forceinline__ float sigf(float x) { return 1.f / (1.f + expf(-x)); }

__device__ __forceinline__ void gload_lds16(const void* g, void* l) {
  __builtin_amdgcn_global_load_lds(
      (const __attribute__((address_space(1))) void*)g,
      (__attribute__((address_space(3))) void*)l, 16, 0, 0);
}

// ---- fence-free coherent access helpers (L3/MALL coherence point, no inv/wbl2) ----
__device__ __forceinline__ bf16x8 ld_frag_sys(const void* p) {
  bf16x8 r;
  asm volatile("global_load_dwordx4 %0, %1, off sc0 sc1" : "=v"(r) : "v"(p));
  return r;
}
__device__ __forceinline__ float ld_f32_sys(const void* p) {
  float r;
  asm volatile("global_load_dword %0, %1, off sc0 sc1" : "=v"(r) : "v"(p));
  return r;
}
__device__ __forceinline__ void st_u16_sys(void* p, unsigned int v) {
  asm volatile("global_store_short %0, %1, off sc0 sc1" :: "v"(p), "v"(v) : "memory");
}
__device__ __forceinline__ void st_f32_sys(void* p, float v) {
  asm volatile("global_store_dword %0, %1, off sc0 sc1" :: "v"(p), "v"(v) : "memory");
}
__device__ __forceinline__ void vm_drain() {
  asm volatile("s_waitcnt vmcnt(0)" ::: "memory");
  __builtin_amdgcn_sched_barrier(0);
}

// relaxed spin: plain sc1 load each iteration, NO acquire fence (no buffer_inv)
__device__ __forceinline__ void spin_ge(int* p, int tgt) {
  int it = 0;
  while (__hip_atomic_load(p, __ATOMIC_RELAXED, __HIP_MEMORY_SCOPE_AGENT) < tgt) {
    __builtin_amdgcn_s_sleep(1);
    if (++it > (1 << 15)) break;   // bailout: wrong answer beats hang
  }
}
__device__ __forceinline__ void flag_set(int* p, int v) {
  __hip_atomic_store(p, v, __ATOMIC_RELAXED, __HIP_MEMORY_SCOPE_AGENT);
}

// ---------------- scale computation ----------------
__global__ void k_init(unsigned int* amax, int* flags) {
  if (threadIdx.x < 8) amax[threadIdx.x] = 0u;
  if (threadIdx.x < 24 * 32) flags[threadIdx.x] = 0;
}

__global__ void k_absmax(const float* __restrict__ p, int n, unsigned int* amax) {
  float m = 0.f;
  for (int i = blockIdx.x * blockDim.x + threadIdx.x; i < n; i += gridDim.x * blockDim.x)
    m = fmaxf(m, fabsf(p[i]));
  #pragma unroll
  for (int off = 32; off > 0; off >>= 1)
    m = fmaxf(m, __shfl_down(m, off));
  if ((threadIdx.x & 63) == 0) atomicMax(amax, __float_as_uint(m));
}

__global__ void k_finalize(const unsigned int* __restrict__ amax, float* __restrict__ sc) {
  int i = threadIdx.x;
  if (i < 6)       sc[i] = fmaxf(__uint_as_float(amax[i]) / 7.0f, 1e-8f);
  else if (i == 6) sc[i] = 1.0f;
}

// ---------------- quantize kernels ----------------
__global__ void k_quant_kbf16(const float* __restrict__ src, ushort* __restrict__ dst,
                              int n4, const float* __restrict__ sc, int slot) {
  int i = blockIdx.x * blockDim.x + threadIdx.x;
  if (i >= n4) return;
  const float s = sc[slot];
  float4 w = ((const float4*)src)[i];
  ushort4 o;
  o.x = bf16b(quant_k_val(w.x, s));
  o.y = bf16b(quant_k_val(w.y, s));
  o.z = bf16b(quant_k_val(w.z, s));
  o.w = bf16b(quant_k_val(w.w, s));
  ((ushort4*)dst)[i] = o;
}

__global__ void k_gather(const int* __restrict__ x, const float* __restrict__ emb,
                         const float* __restrict__ sc, ushort* __restrict__ out) {
  int i = blockIdx.x * blockDim.x + threadIdx.x;
  if (i >= TOK * 64) return;
  int tok = i >> 6, d4 = i & 63;
  const float s = sc[0];
  int row = x[tok];
  float4 w = *(const float4*)(emb + (size_t)row * DM + d4 * 4);
  ushort4 o;
  o.x = bf16b(quant_k_val(w.x, s));
  o.y = bf16b(quant_k_val(w.y, s));
  o.z = bf16b(quant_k_val(w.z, s));
  o.w = bf16b(quant_k_val(w.w, s));
  ((ushort4*)out)[i] = o;
}

// pack A-frags: frag fi = ((g*4+w)*2+i)*8+kf, lane l.
// mode 0 (L0/L1): row = w*256 + g*32 + i*16 + (l&15)   (wave = gate)
// mode 1 (FF):    row = g*128 + (w*2+i)*16 + (l&15)
__global__ void k_packrec(const float* __restrict__ src, bf16x8* __restrict__ dst,
                          const float* __restrict__ sc, int slot, int mode) {
  int q = blockIdx.x * blockDim.x + threadIdx.x;
  if (q >= 512 * 64) return;
  int l = q & 63, kf = (q >> 6) & 7, i = (q >> 9) & 1, w = (q >> 10) & 3, g = (q >> 12) & 7;
  int row = mode ? (g * 128 + (w * 2 + i) * 16 + (l & 15))
                 : (w * 256 + g * 32 + i * 16 + (l & 15));
  int kb = kf * 32 + ((l >> 4) & 3) * 8;
  const float s = sc[slot];
  const float* p = src + (size_t)row * DM + kb;
  bf16x8 o;
  #pragma unroll
  for (int e = 0; e < 8; ++e) o[e] = (short)bf16b(quant_k_val(p[e], s));
  dst[q] = o;
}

// ---------------- 128x128 MFMA bf16 GEMM (validated R1-R4) ----------------
__global__ __launch_bounds__(256) void k_gemm(
    const ushort* __restrict__ A, const ushort* __restrict__ B,
    float* __restrict__ C, int M, int N,
    const float* __restrict__ s1, const float* __restrict__ s2,
    const float* __restrict__ bias1, const float* __restrict__ bias2)
{
  __shared__ alignas(16) ushort As[128 * 64];
  __shared__ alignas(16) ushort Bs[128 * 64];
  const int tid  = threadIdx.x;
  const int lane = tid & 63;
  const int wid  = tid >> 6;
  const size_t m0 = (size_t)blockIdx.x * 128;
  const size_t n0 = (size_t)blockIdx.y * 128;
  const int wm = (wid >> 1) * 64;
  const int wn = (wid & 1) * 64;
  const int r  = tid >> 3;
  const int c8 = (tid & 7) * 8;

  f32x4 acc[4][4];
  #pragma unroll
  for (int m = 0; m < 4; ++m)
    #pragma unroll
    for (int n = 0; n < 4; ++n) acc[m][n] = (f32x4){0.f, 0.f, 0.f, 0.f};

  for (int k0 = 0; k0 < DM; k0 += 64) {
    #pragma unroll
    for (int i = 0; i < 4; ++i) {
      gload_lds16(A + (m0 + i * 32 + r) * DM + k0 + c8, (char*)As + i * 4096 + wid * 1024);
      gload_lds16(B + (n0 + i * 32 + r) * DM + k0 + c8, (char*)Bs + i * 4096 + wid * 1024);
    }
    __syncthreads();
    #pragma unroll
    for (int kk = 0; kk < 2; ++kk) {
      const int ko = (kk * 32 + ((lane >> 4) << 3)) * 2;
      bf16x8 af[4], bfr[4];
      #pragma unroll
      for (int m = 0; m < 4; ++m)
        af[m] = *(const bf16x8*)((const char*)As + (wm + m * 16 + (lane & 15)) * 128 + ko);
      #pragma unroll
      for (int n = 0; n < 4; ++n)
        bfr[n] = *(const bf16x8*)((const char*)Bs + (wn + n * 16 + (lane & 15)) * 128 + ko);
      #pragma unroll
      for (int m = 0; m < 4; ++m)
        #pragma unroll
        for (int n = 0; n < 4; ++n)
          acc[m][n] = __builtin_amdgcn_mfma_f32_16x16x32_bf16(af[m], bfr[n], acc[m][n], 0, 0, 0);
    }
    __syncthreads();
  }

  const float alpha = s1[0] * s2[0];
  const int cl = lane & 15;
  const int rq = (lane >> 4) * 4;
  #pragma unroll
  for (int n = 0; n < 4; ++n) {
    const size_t col = n0 + wn + n * 16 + cl;
    float badd = 0.f;
    if (bias1) badd += bias1[col];
    if (bias2) badd += bias2[col];
    #pragma unroll
    for (int m = 0; m < 4; ++m) {
      const size_t rowb = m0 + wm + m * 16 + rq;
      #pragma unroll
      for (int q = 0; q < 4; ++q)
        C[(rowb + q) * (size_t)N + col] = acc[m][n][q] * alpha + badd;
    }
  }
}

// ---------------- register-resident MFMA LSTM, fence-free 24-block pipeline ----------------
// Active: bid%8==0 (XCD0-colocated), m=bid>>3: 0-7 L0[g], 8-15 FF[g], 16-23 L1[g].
// 256 threads (4 waves; wave=gate for L0/L1). A-frags (int4 codes) in VGPRs all 512 steps.
// Exchange: h 3-plane bf16 B-frags + xg1, all via sc0sc1 (L3-coherent, NO fences).
// Flags: relaxed atomics, single writer, own 128B line. 4-deep slot buffers.
__global__ __launch_bounds__(256) void k_rec3(
    const bf16x8* __restrict__ WL0, const bf16x8* __restrict__ WFF,
    const bf16x8* __restrict__ WL1,
    const float* __restrict__ XG, float* __restrict__ XG1,
    ushort* __restrict__ HX0, ushort* __restrict__ HX1,
    ushort* __restrict__ HOUT, int* __restrict__ flags,
    const float* __restrict__ sc,
    const float* __restrict__ bih, const float* __restrict__ bhh)
{
  if (blockIdx.x & 7) return;
  const int m = blockIdx.x >> 3;
  if (m >= 24) return;
  const int role = m >> 3;          // 0 L0, 1 FF, 2 L1
  const int g = m & 7;
  const int tid = threadIdx.x, lane = tid & 63, w = tid >> 6;
  const int kg = lane >> 4, cb = lane & 15;
  const int r0 = tid & 31, b0 = tid >> 5;
  __shared__ float Gl[4 * 32 * 17];

  bf16x8 a[16];
  const bf16x8* WP = (role == 0) ? WL0 : (role == 1 ? WFF : WL1);
  #pragma unroll
  for (int i = 0; i < 2; ++i)
    #pragma unroll
    for (int kf = 0; kf < 8; ++kf)
      a[i * 8 + kf] = WP[((((g * 4 + w) * 2 + i) * 8 + kf) << 6) + lane];

  if (role == 0) {
    // ================= layer-0 recurrence =================
    const float s2 = sc[2];
    float cc[2] = {0.f, 0.f};
    for (int t = 0; t < SEQ; ++t) {
      float xv[2][4];                       // plain cached loads (static data)
      #pragma unroll
      for (int i = 0; i < 2; ++i)
        #pragma unroll
        for (int gt = 0; gt < 4; ++gt)
          xv[i][gt] = XG[(size_t)((b0 + i * 8) * 512 + t) * G4 + gt * 256 + g * 32 + r0];
      // peers >= t (h0[t-1] published); FF >= t-3 (slot t&3 free)
      if (tid < 16) spin_ge(flags + tid * 32, (tid < 8) ? t : t - 3);
      __syncthreads();
      f32x4 acc0 = {0.f,0.f,0.f,0.f}, acc1 = {0.f,0.f,0.f,0.f};
      if (t > 0) {
        const char* hb = (const char*)HX0 + (size_t)((t - 1) & 3) * 24576 + lane * 16;
        bf16x8 bfr[24];
        #pragma unroll
        for (int f = 0; f < 24; ++f) bfr[f] = ld_frag_sys(hb + (f << 10));
        vm_drain();
        #pragma unroll
        for (int kf = 0; kf < 8; ++kf)
          #pragma unroll
          for (int p = 0; p < 3; ++p) {
            acc0 = __builtin_amdgcn_mfma_f32_16x16x32_bf16(a[kf],     bfr[kf*3+p], acc0, 0, 0, 0);
            acc1 = __builtin_amdgcn_mfma_f32_16x16x32_bf16(a[8 + kf], bfr[kf*3+p], acc1, 0, 0, 0);
          }
      }
      #pragma unroll
      for (int q = 0; q < 4; ++q) {
        Gl[(w * 32      + kg * 4 + q) * 17 + cb] = acc0[q];
        Gl[(w * 32 + 16 + kg * 4 + q) * 17 + cb] = acc1[q];
      }
      __syncthreads();
      const int sl = t & 3;
      #pragma unroll
      for (int i = 0; i < 2; ++i) {
        const int b = b0 + i * 8;
        float g0 = xv[i][0] + s2 * Gl[(0 * 32 + r0) * 17 + b];
        float g1 = xv[i][1] + s2 * Gl[(1 * 32 + r0) * 17 + b];
        float g2 = xv[i][2] + s2 * Gl[(2 * 32 + r0) * 17 + b];
        float g3 = xv[i][3] + s2 * Gl[(3 * 32 + r0) * 17 + b];
        float i_ = sigf(g0), f_ = sigf(g1), gg = tanhf(g2), o_ = sigf(g3);
        cc[i] = f_ * cc[i] + i_ * gg;
        float h = o_ * tanhf(cc[i]);
        unsigned short p1 = bf16b(h);
        float r1 = h - bf16f((short)p1);
        unsigned short p2 = bf16b(r1);
        float r2 = r1 - bf16f((short)p2);
        unsigned short p3 = bf16b(r2);
        const int l2 = ((r0 >> 3) << 4) | b;
        ushort* pb = HX0 + ((size_t)sl * 24 + g * 3) * 512 + l2 * 8 + (r0 & 7);
        st_u16_sys(pb,        p1);
        st_u16_sys(pb + 512,  p2);
        st_u16_sys(pb + 1024, p3);
      }
      vm_drain();                          // own sys-stores complete at L3
      __syncthreads();                     // all threads' stores done
      if (tid == 0) flag_set(flags + g * 32, t + 1);
    }
  } else if (role == 1) {
    // ================= feed-forward xg1 = s3*(wih1.h0[t]) + bias =================
    const float s3 = sc[3];
    float br[2][4];
    #pragma unroll
    for (int i = 0; i < 2; ++i)
      #pragma unroll
      for (int q = 0; q < 4; ++q) {
        int j = g * 128 + (w * 2 + i) * 16 + kg * 4 + q;
        br[i][q] = bih[G4 + j] + bhh[G4 + j];
      }
    for (int t = 0; t < SEQ; ++t) {
      // L0 >= t+1 (h0[t]); L1 >= t-3 (xg1 slot t&3 free)
      if (tid < 16) spin_ge(flags + ((tid < 8) ? tid : tid + 8) * 32, (tid < 8) ? t + 1 : t - 3);
      __syncthreads();
      const int sl = t & 3;
      const char* hb = (const char*)HX0 + (size_t)sl * 24576 + lane * 16;
      bf16x8 bfr[24];
      #pragma unroll
      for (int f = 0; f < 24; ++f) bfr[f] = ld_frag_sys(hb + (f << 10));
      vm_drain();
      f32x4 acc0 = {0.f,0.f,0.f,0.f}, acc1 = {0.f,0.f,0.f,0.f};
      #pragma unroll
      for (int kf = 0; kf < 8; ++kf)
        #pragma unroll
        for (int p = 0; p < 3; ++p) {
          acc0 = __builtin_amdgcn_mfma_f32_16x16x32_bf16(a[kf],     bfr[kf*3+p], acc0, 0, 0, 0);
          acc1 = __builtin_amdgcn_mfma_f32_16x16x32_bf16(a[8 + kf], bfr[kf*3+p], acc1, 0, 0, 0);
        }
      #pragma unroll
      for (int i = 0; i < 2; ++i)
        #pragma unroll
        for (int q = 0; q < 4; ++q) {
          int j = g * 128 + (w * 2 + i) * 16 + kg * 4 + q;
          float v = (i ? acc1[q] : acc0[q]) * s3 + br[i][q];
          st_f32_sys(XG1 + ((size_t)sl * G4 + j) * 16 + cb, v);
        }
      vm_drain();
      __syncthreads();
      if (tid == 0) flag_set(flags + (8 + g) * 32, t + 1);
    }
  } else {
    // ================= layer-1 recurrence =================
    const float s4 = sc[4];
    float cc[2] = {0.f, 0.f};
    for (int t = 0; t < SEQ; ++t) {
      // FF >= t+1 (xg1[t]); L1 peers >= t (h1[t-1])
      if (tid < 16) spin_ge(flags + (8 + tid) * 32, (tid < 8) ? t + 1 : t);
      __syncthreads();
      const int sl = t & 3;
      float xv[2][4];
      #pragma unroll
      for (int i = 0; i < 2; ++i)
        #pragma unroll
        for (int gt = 0; gt < 4; ++gt)
          xv[i][gt] = ld_f32_sys(XG1 + ((size_t)sl * G4 + gt * 256 + g * 32 + r0) * 16 + b0 + i * 8);
      f32x4 acc0 = {0.f,0.f,0.f,0.f}, acc1 = {0.f,0.f,0.f,0.f};
      if (t > 0) {
        const char* hb = (const char*)HX1 + (size_t)((t - 1) & 3) * 24576 + lane * 16;
        bf16x8 bfr[24];
        #pragma unroll
        for (int f = 0; f < 24; ++f) bfr[f] = ld_frag_sys(hb + (f << 10));
        vm_drain();
        #pragma unroll
        for (int kf = 0; kf < 8; ++kf)
          #pragma unroll
          for (int p = 0; p < 3; ++p) {
            acc0 = __builtin_amdgcn_mfma_f32_16x16x32_bf16(a[kf],     bfr[kf*3+p], acc0, 0, 0, 0);
            acc1 = __builtin_amdgcn_mfma_f32_16x16x32_bf16(a[8 + kf], bfr[kf*3+p], acc1, 0, 0, 0);
          }
      } else {
        vm_drain();                        // drain the xg1 loads
      }
      #pragma unroll
      for (int q = 0; q < 4; ++q) {
        Gl[(w * 32      + kg * 4 + q) * 17 + cb] = acc0[q];
        Gl[(w * 32 + 16 + kg * 4 + q) * 17 + cb] = acc1[q];
      }
      __syncthreads();
      #pragma unroll
      for (int i = 0; i < 2; ++i) {
        const int b = b0 + i * 8;
        float g0 = xv[i][0] + s4 * Gl[(0 * 32 + r0) * 17 + b];
        float g1 = xv[i][1] + s4 * Gl[(1 * 32 + r0) * 17 + b];
        float g2 = xv[i][2] + s4 * Gl[(2 * 32 + r0) * 17 + b];
        float g3 = xv[i][3] + s4 * Gl[(3 * 32 + r0) * 17 + b];
        float i_ = sigf(g0), f_ = sigf(g1), gg = tanhf(g2), o_ = sigf(g3);
        cc[i] = f_ * cc[i] + i_ * gg;
        float h = o_ * tanhf(cc[i]);
        unsigned short p1 = bf16b(h);
        float r1 = h - bf16f((short)p1);
        unsigned short p2 = bf16b(r1);
        float r2 = r1 - bf16f((short)p2);
        unsigned short p3 = bf16b(r2);
        HOUT[(size_t)(b * 512 + t) * 256 + g * 32 + r0] = p1;   // plain (next dispatch)
        const int l2 = ((r0 >> 3) << 4) | b;
        ushort* pb = HX1 + ((size_t)(t & 3) * 24 + g * 3) * 512 + l2 * 8 + (r0 & 7);
        st_u16_sys(pb,        p1);
        st_u16_sys(pb + 512,  p2);
        st_u16_sys(pb + 1024, p3);
      }
      vm_drain();
      __syncthreads();
      if (tid == 0) flag_set(flags + (16 + g) * 32, t + 1);
    }
  }
}

// ---------------- launch ----------------
extern "C" void kernel_launch(void* const* d_in, const int* in_sizes, int n_in,
                              void* d_out, int out_size, void* d_ws, size_t ws_size,
                              hipStream_t stream) {
  const int*   x   = (const int*)d_in[0];
  const float* emb = (const float*)d_in[1];
  const float* wih = (const float*)d_in[2];   // [2,1024,256]
  const float* bih = (const float*)d_in[3];   // [2,1024]
  const float* whh = (const float*)d_in[4];
  const float* bhh = (const float*)d_in[5];
  const float* fcw = (const float*)d_in[6];   // [32000,256]
  const float* fcb = (const float*)d_in[7];
  float* out = (float*)d_out;

  char* ws = (char*)d_ws;
  float*        SC    = (float*)(ws + OF_SC);
  unsigned int* AMAX  = (unsigned int*)(ws + OF_AMAX);
  int*          FLAGS = (int*)(ws + OF_FLAG);
  ushort*       KEMB  = (ushort*)(ws + OF_KEMB);
  ushort*       KWIH0 = (ushort*)(ws + OF_KWIH0);
  ushort*       KFC   = (ushort*)(ws + OF_KFC);
  bf16x8*       WL0   = (bf16x8*)(ws + OF_WL0);
  bf16x8*       WFF   = (bf16x8*)(ws + OF_WFF);
  bf16x8*       WL1   = (bf16x8*)(ws + OF_WL1);
  float*        XG1   = (float*)(ws + OF_XG1);
  ushort*       HX0   = (ushort*)(ws + OF_HX0);
  ushort*       HX1   = (ushort*)(ws + OF_HX1);
  float*        XG    = (float*)(ws + OF_XG);
  ushort*       HOUT  = (ushort*)(ws + OF_HOUT);

  const int nw = G4 * DM;

  k_init<<<1, 1024, 0, stream>>>(AMAX, FLAGS);
  k_absmax<<<2048, 256, 0, stream>>>(emb,      VOC * DM, AMAX + 0);
  k_absmax<<<256,  256, 0, stream>>>(wih,      nw,       AMAX + 1);
  k_absmax<<<256,  256, 0, stream>>>(whh,      nw,       AMAX + 2);
  k_absmax<<<256,  256, 0, stream>>>(wih + nw, nw,       AMAX + 3);
  k_absmax<<<256,  256, 0, stream>>>(whh + nw, nw,       AMAX + 4);
  k_absmax<<<2048, 256, 0, stream>>>(fcw,      VOC * DM, AMAX + 5);
  k_finalize<<<1, 8, 0, stream>>>(AMAX, SC);

  k_gather<<<TOK * 64 / 256, 256, 0, stream>>>(x, emb, SC, KEMB);
  k_quant_kbf16<<<nw / 4 / 256,       256, 0, stream>>>(wih, KWIH0, nw / 4,       SC, 1);
  k_quant_kbf16<<<VOC * DM / 4 / 256, 256, 0, stream>>>(fcw, KFC,   VOC * DM / 4, SC, 5);
  k_packrec<<<128, 256, 0, stream>>>(whh,      WL0, SC, 2, 0);
  k_packrec<<<128, 256, 0, stream>>>(wih + nw, WFF, SC, 3, 1);
  k_packrec<<<128, 256, 0, stream>>>(whh + nw, WL1, SC, 4, 0);

  // xgates(layer0) = s0*s1 * (k_emb @ k_wih0^T) + b_ih0 + b_hh0  (integer-exact MFMA)
  dim3 g1(TOK / 128, G4 / 128);
  k_gemm<<<g1, 256, 0, stream>>>(KEMB, KWIH0, XG, TOK, G4, SC + 0, SC + 1, bih, bhh);

  k_rec3<<<192, 256, 0, stream>>>(WL0, WFF, WL1, XG, XG1, HX0, HX1, HOUT,
                                  FLAGS, SC, bih, bhh);

  // logits = s_fc * (h @ k_fc^T) + fc_b
  dim3 g2(TOK / 128, VOC / 128);
  k_gemm<<<g2, 256, 0, stream>>>(HOUT, KFC, out, TOK, VOC, SC + 5, SC + 6, fcb, nullptr);
}

// Round 6
// 2784.074 us; speedup vs baseline: 5.7387x; 1.0318x over previous
//
#include <hip/hip_runtime.h>
#include <hip/hip_bf16.h>
#include <stdint.h>

typedef __attribute__((ext_vector_type(8))) short bf16x8;
typedef __attribute__((ext_vector_type(4))) float f32x4;

#define NB   16
#define SEQ  512
#define DM   256
#define G4   1024
#define VOC  32000
#define TOK  (NB*SEQ)          // 8192 tokens

// ---------------- workspace layout (bytes) ----------------
#define OF_SC     0                                  // float[8]
#define OF_AMAX   64                                 // uint[8]
#define OF_FLAG   128                                // int[1024]: F0[8*32], F1[8*32] (128B/flag)
#define OF_KEMB   16384                              // bf16 codes [8192,256]
#define OF_KWIH0  (OF_KEMB  + TOK*DM*2)              // bf16 codes [1024,256]
#define OF_KFC    (OF_KWIH0 + G4*DM*2)               // bf16 codes [32000,256]
#define OF_WL0    (OF_KFC   + VOC*DM*2)              // whh0 A-frags 512KB
#define OF_WFF    (OF_WL0   + 512*64*16)             // wih1 A-frags 512KB (mode-0 layout now)
#define OF_WL1    (OF_WFF   + 512*64*16)             // whh1 A-frags 512KB
#define OF_HX0    (OF_WL1   + 512*64*16)             // h0 frags [4 slots][8 g][2 p][1KB] = 64KB
#define OF_HX1    (OF_HX0   + 4*16384)               // h1 frags, same (64KB)
#define OF_XG     (OF_HX1   + 4*16384)               // f32 [8192,1024] layer0 input gates
#define OF_HOUT   (OF_XG    + (size_t)TOK*G4*4)      // bf16 [8192,256] h1 (FC input)

__device__ __forceinline__ unsigned short bf16b(float f) {
  __hip_bfloat16 h = __float2bfloat16(f);
  return *reinterpret_cast<unsigned short*>(&h);
}
__device__ __forceinline__ float bf16f(short u) {
  return __uint_as_float(((unsigned)(unsigned short)u) << 16);
}
__device__ __forceinline__ float quant_k_val(float w, float s) {
  float k = rintf(w / s);                       // round-half-even == jnp.round
  return fminf(fmaxf(k, -8.f), 7.f);
}
__device__ __forceinline__ float sigf(float x) { return 1.f / (1.f + expf(-x)); }

__device__ __forceinline__ void gload_lds16(const void* g, void* l) {
  __builtin_amdgcn_global_load_lds(
      (const __attribute__((address_space(1))) void*)g,
      (__attribute__((address_space(3))) void*)l, 16, 0, 0);
}

// ---- fence-free coherent access (L3 coherence point; placement-independent) ----
__device__ __forceinline__ bf16x8 ld_frag_sys(const void* p) {
  bf16x8 r;
  asm volatile("global_load_dwordx4 %0, %1, off sc0 sc1" : "=v"(r) : "v"(p));
  return r;
}
__device__ __forceinline__ void st_frag_sys(void* p, bf16x8 v) {
  asm volatile("global_store_dwordx4 %0, %1, off sc0 sc1" :: "v"(p), "v"(v) : "memory");
}
__device__ __forceinline__ void vm_drain() {
  asm volatile("s_waitcnt vmcnt(0)" ::: "memory");
  __builtin_amdgcn_sched_barrier(0);
}

// relaxed spin: no acquire fence (no buffer_inv); data moves via sc0sc1 path
__device__ __forceinline__ void spin_ge(int* p, int tgt) {
  int it = 0;
  while (__hip_atomic_load(p, __ATOMIC_RELAXED, __HIP_MEMORY_SCOPE_AGENT) < tgt) {
    __builtin_amdgcn_s_sleep(1);
    if (++it > (1 << 15)) break;   // bailout: wrong answer beats hang
  }
}
__device__ __forceinline__ void flag_set(int* p, int v) {
  __hip_atomic_store(p, v, __ATOMIC_RELAXED, __HIP_MEMORY_SCOPE_AGENT);
}

// ---------------- scale computation ----------------
__global__ void k_init(unsigned int* amax, int* flags) {
  if (threadIdx.x < 8) amax[threadIdx.x] = 0u;
  flags[threadIdx.x] = 0;   // 1024 threads
}

__global__ void k_absmax(const float* __restrict__ p, int n, unsigned int* amax) {
  float m = 0.f;
  for (int i = blockIdx.x * blockDim.x + threadIdx.x; i < n; i += gridDim.x * blockDim.x)
    m = fmaxf(m, fabsf(p[i]));
  #pragma unroll
  for (int off = 32; off > 0; off >>= 1)
    m = fmaxf(m, __shfl_down(m, off));
  if ((threadIdx.x & 63) == 0) atomicMax(amax, __float_as_uint(m));
}

__global__ void k_finalize(const unsigned int* __restrict__ amax, float* __restrict__ sc) {
  int i = threadIdx.x;
  if (i < 6)       sc[i] = fmaxf(__uint_as_float(amax[i]) / 7.0f, 1e-8f);
  else if (i == 6) sc[i] = 1.0f;
}

// ---------------- quantize kernels ----------------
__global__ void k_quant_kbf16(const float* __restrict__ src, ushort* __restrict__ dst,
                              int n4, const float* __restrict__ sc, int slot) {
  int i = blockIdx.x * blockDim.x + threadIdx.x;
  if (i >= n4) return;
  const float s = sc[slot];
  float4 w = ((const float4*)src)[i];
  ushort4 o;
  o.x = bf16b(quant_k_val(w.x, s));
  o.y = bf16b(quant_k_val(w.y, s));
  o.z = bf16b(quant_k_val(w.z, s));
  o.w = bf16b(quant_k_val(w.w, s));
  ((ushort4*)dst)[i] = o;
}

__global__ void k_gather(const int* __restrict__ x, const float* __restrict__ emb,
                         const float* __restrict__ sc, ushort* __restrict__ out) {
  int i = blockIdx.x * blockDim.x + threadIdx.x;
  if (i >= TOK * 64) return;
  int tok = i >> 6, d4 = i & 63;
  const float s = sc[0];
  int row = x[tok];
  float4 w = *(const float4*)(emb + (size_t)row * DM + d4 * 4);
  ushort4 o;
  o.x = bf16b(quant_k_val(w.x, s));
  o.y = bf16b(quant_k_val(w.y, s));
  o.z = bf16b(quant_k_val(w.z, s));
  o.w = bf16b(quant_k_val(w.w, s));
  ((ushort4*)out)[i] = o;
}

// pack A-frags (mode 0, validated R3-R5): frag fi = ((g*4+wv)*2+i)*8+c, lane l:
// row = wv*256 + g*32 + i*16 + (l&15), k = c*32 + ((l>>4)&3)*8 + e
__global__ void k_packrec(const float* __restrict__ src, bf16x8* __restrict__ dst,
                          const float* __restrict__ sc, int slot, int mode) {
  int q = blockIdx.x * blockDim.x + threadIdx.x;
  if (q >= 512 * 64) return;
  int l = q & 63, kf = (q >> 6) & 7, i = (q >> 9) & 1, w = (q >> 10) & 3, g = (q >> 12) & 7;
  int row = mode ? (g * 128 + (w * 2 + i) * 16 + (l & 15))
                 : (w * 256 + g * 32 + i * 16 + (l & 15));
  int kb = kf * 32 + ((l >> 4) & 3) * 8;
  const float s = sc[slot];
  const float* p = src + (size_t)row * DM + kb;
  bf16x8 o;
  #pragma unroll
  for (int e = 0; e < 8; ++e) o[e] = (short)bf16b(quant_k_val(p[e], s));
  dst[q] = o;
}

// ---------------- 128x128 MFMA bf16 GEMM (validated R1-R5) ----------------
__global__ __launch_bounds__(256) void k_gemm(
    const ushort* __restrict__ A, const ushort* __restrict__ B,
    float* __restrict__ C, int M, int N,
    const float* __restrict__ s1, const float* __restrict__ s2,
    const float* __restrict__ bias1, const float* __restrict__ bias2)
{
  __shared__ alignas(16) ushort As[128 * 64];
  __shared__ alignas(16) ushort Bs[128 * 64];
  const int tid  = threadIdx.x;
  const int lane = tid & 63;
  const int wid  = tid >> 6;
  const size_t m0 = (size_t)blockIdx.x * 128;
  const size_t n0 = (size_t)blockIdx.y * 128;
  const int wm = (wid >> 1) * 64;
  const int wn = (wid & 1) * 64;
  const int r  = tid >> 3;
  const int c8 = (tid & 7) * 8;

  f32x4 acc[4][4];
  #pragma unroll
  for (int m = 0; m < 4; ++m)
    #pragma unroll
    for (int n = 0; n < 4; ++n) acc[m][n] = (f32x4){0.f, 0.f, 0.f, 0.f};

  for (int k0 = 0; k0 < DM; k0 += 64) {
    #pragma unroll
    for (int i = 0; i < 4; ++i) {
      gload_lds16(A + (m0 + i * 32 + r) * DM + k0 + c8, (char*)As + i * 4096 + wid * 1024);
      gload_lds16(B + (n0 + i * 32 + r) * DM + k0 + c8, (char*)Bs + i * 4096 + wid * 1024);
    }
    __syncthreads();
    #pragma unroll
    for (int kk = 0; kk < 2; ++kk) {
      const int ko = (kk * 32 + ((lane >> 4) << 3)) * 2;
      bf16x8 af[4], bfr[4];
      #pragma unroll
      for (int m = 0; m < 4; ++m)
        af[m] = *(const bf16x8*)((const char*)As + (wm + m * 16 + (lane & 15)) * 128 + ko);
      #pragma unroll
      for (int n = 0; n < 4; ++n)
        bfr[n] = *(const bf16x8*)((const char*)Bs + (wn + n * 16 + (lane & 15)) * 128 + ko);
      #pragma unroll
      for (int m = 0; m < 4; ++m)
        #pragma unroll
        for (int n = 0; n < 4; ++n)
          acc[m][n] = __builtin_amdgcn_mfma_f32_16x16x32_bf16(af[m], bfr[n], acc[m][n], 0, 0, 0);
    }
    __syncthreads();
  }

  const float alpha = s1[0] * s2[0];
  const int cl = lane & 15;
  const int rq = (lane >> 4) * 4;
  #pragma unroll
  for (int n = 0; n < 4; ++n) {
    const size_t col = n0 + wn + n * 16 + cl;
    float badd = 0.f;
    if (bias1) badd += bias1[col];
    if (bias2) badd += bias2[col];
    #pragma unroll
    for (int m = 0; m < 4; ++m) {
      const size_t rowb = m0 + wm + m * 16 + rq;
      #pragma unroll
      for (int q = 0; q < 4; ++q)
        C[(rowb + q) * (size_t)N + col] = acc[m][n][q] * alpha + badd;
    }
  }
}

// ---------------- 2-stage register-resident MFMA LSTM ----------------
// 16 active blocks (bid%8==0): m=0..7 L0[g], m=8..15 L1[g] (FF merged, K=512).
// 512 threads = 8 waves; wave w: gate = w>>1, row-tile i = w&1; rows = gate*256+g*32+i*16.
// h exchange: 2 exact bf16 planes (h = p1 + p2, err <= 2^-17), frag-linear 2KB/block/step,
// published via LDS-pack + coalesced dwordx4 sc0sc1; consumed as 16B/lane frag loads.
// Flags: relaxed atomics, single writer, 128B lines. Slot depth 4.
__global__ __launch_bounds__(512) void k_rec4(
    const bf16x8* __restrict__ WL0, const bf16x8* __restrict__ WFF,
    const bf16x8* __restrict__ WL1, const float* __restrict__ XG,
    ushort* __restrict__ HX0, ushort* __restrict__ HX1,
    ushort* __restrict__ HOUT, int* __restrict__ flags,
    const float* __restrict__ sc,
    const float* __restrict__ bih, const float* __restrict__ bhh)
{
  if (blockIdx.x & 7) return;
  const int m = blockIdx.x >> 3;
  if (m >= 16) return;
  const int role = m >> 3, g = m & 7;
  const int tid = threadIdx.x, lane = tid & 63, w = tid >> 6;
  const int kg = lane >> 4, cb = lane & 15;
  const int r0 = tid & 31, b = tid >> 5;          // act coords: k-row, batch
  const int gw = (g * 4 + (w >> 1)) * 2 + (w & 1);
  __shared__ float Gl[4 * 32 * 17];
  __shared__ alignas(16) ushort hp[1024];          // 2 planes x 64 lanes x 8 halves
  int* F0 = flags;
  int* F1 = flags + 8 * 32;
  const int fl = ((r0 >> 3) << 4) | b;             // frag lane for produced h(k=r0,b)

  if (role == 0) {
    // ================= layer-0 recurrence =================
    bf16x8 a[8];
    #pragma unroll
    for (int c = 0; c < 8; ++c) a[c] = WL0[((gw * 8 + c) << 6) + lane];
    const float s2 = sc[2];
    float cc = 0.f;
    for (int t = 0; t < SEQ; ++t) {
      // prefetch xg (plain cached; in flight during spin)
      const size_t xb = ((size_t)(b * 512 + t) << 10) + g * 32 + r0;
      float xv0 = XG[xb], xv1 = XG[xb + 256], xv2 = XG[xb + 512], xv3 = XG[xb + 768];
      // peers >= t (h0[t-1]); L1 >= t-3 (HX0 slot t&3 free)
      if (tid < 16) spin_ge((tid < 8) ? F0 + tid * 32 : F1 + (tid - 8) * 32,
                            (tid < 8) ? t : t - 3);
      __syncthreads();
      f32x4 acc = {0.f, 0.f, 0.f, 0.f};
      if (t > 0) {
        const char* hb = (const char*)HX0 + (size_t)((t - 1) & 3) * 16384 + lane * 16;
        bf16x8 bp[16];
        #pragma unroll
        for (int c = 0; c < 8; ++c) {
          bp[2 * c]     = ld_frag_sys(hb + c * 2048);
          bp[2 * c + 1] = ld_frag_sys(hb + c * 2048 + 1024);
        }
        vm_drain();
        #pragma unroll
        for (int c = 0; c < 8; ++c) {
          acc = __builtin_amdgcn_mfma_f32_16x16x32_bf16(a[c], bp[2 * c],     acc, 0, 0, 0);
          acc = __builtin_amdgcn_mfma_f32_16x16x32_bf16(a[c], bp[2 * c + 1], acc, 0, 0, 0);
        }
      }
      #pragma unroll
      for (int q = 0; q < 4; ++q)
        Gl[((w >> 1) * 32 + (w & 1) * 16 + kg * 4 + q) * 17 + cb] = acc[q];
      __syncthreads();
      {
        float g0 = xv0 + s2 * Gl[(0 * 32 + r0) * 17 + b];
        float g1 = xv1 + s2 * Gl[(1 * 32 + r0) * 17 + b];
        float g2 = xv2 + s2 * Gl[(2 * 32 + r0) * 17 + b];
        float g3 = xv3 + s2 * Gl[(3 * 32 + r0) * 17 + b];
        float i_ = sigf(g0), f_ = sigf(g1), gg = tanhf(g2), o_ = sigf(g3);
        cc = f_ * cc + i_ * gg;
        float h = o_ * tanhf(cc);
        unsigned short p1 = bf16b(h);
        float r1 = h - bf16f((short)p1);
        unsigned short p2 = bf16b(r1);
        hp[fl * 8 + (r0 & 7)]       = p1;
        hp[512 + fl * 8 + (r0 & 7)] = p2;
      }
      __syncthreads();
      if (tid < 128)
        st_frag_sys(HX0 + (size_t)(t & 3) * 8192 + g * 1024 + tid * 8,
                    *(const bf16x8*)(hp + tid * 8));
      vm_drain();
      __syncthreads();
      if (tid == 0) flag_set(F0 + g * 32, t + 1);
    }
  } else {
    // ================= layer-1 (FF merged): gates = b + s3*wih1.h0[t] + s4*whh1.h1[t-1] ====
    bf16x8 aI[8], aH[8];
    #pragma unroll
    for (int c = 0; c < 8; ++c) {
      aI[c] = WFF[((gw * 8 + c) << 6) + lane];
      aH[c] = WL1[((gw * 8 + c) << 6) + lane];
    }
    const float s3 = sc[3], s4 = sc[4];
    const int jb = G4 + g * 32 + r0;
    const float bb0 = bih[jb]       + bhh[jb];
    const float bb1 = bih[jb + 256] + bhh[jb + 256];
    const float bb2 = bih[jb + 512] + bhh[jb + 512];
    const float bb3 = bih[jb + 768] + bhh[jb + 768];
    float cc = 0.f;
    for (int t = 0; t < SEQ; ++t) {
      // phase A: self-recurrence part first (ready early; overlaps L0's tail)
      if (tid < 8) spin_ge(F1 + tid * 32, t);      // peers h1[t-1]
      __syncthreads();
      f32x4 accH = {0.f, 0.f, 0.f, 0.f};
      if (t > 0) {
        const char* hb = (const char*)HX1 + (size_t)((t - 1) & 3) * 16384 + lane * 16;
        bf16x8 bp[16];
        #pragma unroll
        for (int c = 0; c < 8; ++c) {
          bp[2 * c]     = ld_frag_sys(hb + c * 2048);
          bp[2 * c + 1] = ld_frag_sys(hb + c * 2048 + 1024);
        }
        vm_drain();
        #pragma unroll
        for (int c = 0; c < 8; ++c) {
          accH = __builtin_amdgcn_mfma_f32_16x16x32_bf16(aH[c], bp[2 * c],     accH, 0, 0, 0);
          accH = __builtin_amdgcn_mfma_f32_16x16x32_bf16(aH[c], bp[2 * c + 1], accH, 0, 0, 0);
        }
      }
      // phase B: input part gated on L0
      if (tid < 8) spin_ge(F0 + tid * 32, t + 1);  // h0[t]
      __syncthreads();
      f32x4 accI = {0.f, 0.f, 0.f, 0.f};
      {
        const char* hb = (const char*)HX0 + (size_t)(t & 3) * 16384 + lane * 16;
        bf16x8 bp[16];
        #pragma unroll
        for (int c = 0; c < 8; ++c) {
          bp[2 * c]     = ld_frag_sys(hb + c * 2048);
          bp[2 * c + 1] = ld_frag_sys(hb + c * 2048 + 1024);
        }
        vm_drain();
        #pragma unroll
        for (int c = 0; c < 8; ++c) {
          accI = __builtin_amdgcn_mfma_f32_16x16x32_bf16(aI[c], bp[2 * c],     accI, 0, 0, 0);
          accI = __builtin_amdgcn_mfma_f32_16x16x32_bf16(aI[c], bp[2 * c + 1], accI, 0, 0, 0);
        }
      }
      #pragma unroll
      for (int q = 0; q < 4; ++q)
        Gl[((w >> 1) * 32 + (w & 1) * 16 + kg * 4 + q) * 17 + cb] = s3 * accI[q] + s4 * accH[q];
      __syncthreads();
      {
        float g0 = bb0 + Gl[(0 * 32 + r0) * 17 + b];
        float g1 = bb1 + Gl[(1 * 32 + r0) * 17 + b];
        float g2 = bb2 + Gl[(2 * 32 + r0) * 17 + b];
        float g3 = bb3 + Gl[(3 * 32 + r0) * 17 + b];
        float i_ = sigf(g0), f_ = sigf(g1), gg = tanhf(g2), o_ = sigf(g3);
        cc = f_ * cc + i_ * gg;
        float h = o_ * tanhf(cc);
        unsigned short p1 = bf16b(h);
        float r1 = h - bf16f((short)p1);
        unsigned short p2 = bf16b(r1);
        HOUT[((size_t)b * 512 + t) * 256 + g * 32 + r0] = p1;   // plain; next dispatch reads
        hp[fl * 8 + (r0 & 7)]       = p1;
        hp[512 + fl * 8 + (r0 & 7)] = p2;
      }
      __syncthreads();
      if (tid < 128)
        st_frag_sys(HX1 + (size_t)(t & 3) * 8192 + g * 1024 + tid * 8,
                    *(const bf16x8*)(hp + tid * 8));
      vm_drain();
      __syncthreads();
      if (tid == 0) flag_set(F1 + g * 32, t + 1);
    }
  }
}

// ---------------- launch ----------------
extern "C" void kernel_launch(void* const* d_in, const int* in_sizes, int n_in,
                              void* d_out, int out_size, void* d_ws, size_t ws_size,
                              hipStream_t stream) {
  const int*   x   = (const int*)d_in[0];
  const float* emb = (const float*)d_in[1];
  const float* wih = (const float*)d_in[2];   // [2,1024,256]
  const float* bih = (const float*)d_in[3];   // [2,1024]
  const float* whh = (const float*)d_in[4];
  const float* bhh = (const float*)d_in[5];
  const float* fcw = (const float*)d_in[6];   // [32000,256]
  const float* fcb = (const float*)d_in[7];
  float* out = (float*)d_out;

  char* ws = (char*)d_ws;
  float*        SC    = (float*)(ws + OF_SC);
  unsigned int* AMAX  = (unsigned int*)(ws + OF_AMAX);
  int*          FLAGS = (int*)(ws + OF_FLAG);
  ushort*       KEMB  = (ushort*)(ws + OF_KEMB);
  ushort*       KWIH0 = (ushort*)(ws + OF_KWIH0);
  ushort*       KFC   = (ushort*)(ws + OF_KFC);
  bf16x8*       WL0   = (bf16x8*)(ws + OF_WL0);
  bf16x8*       WFF   = (bf16x8*)(ws + OF_WFF);
  bf16x8*       WL1   = (bf16x8*)(ws + OF_WL1);
  ushort*       HX0   = (ushort*)(ws + OF_HX0);
  ushort*       HX1   = (ushort*)(ws + OF_HX1);
  float*        XG    = (float*)(ws + OF_XG);
  ushort*       HOUT  = (ushort*)(ws + OF_HOUT);

  const int nw = G4 * DM;

  k_init<<<1, 1024, 0, stream>>>(AMAX, FLAGS);
  k_absmax<<<2048, 256, 0, stream>>>(emb,      VOC * DM, AMAX + 0);
  k_absmax<<<256,  256, 0, stream>>>(wih,      nw,       AMAX + 1);
  k_absmax<<<256,  256, 0, stream>>>(whh,      nw,       AMAX + 2);
  k_absmax<<<256,  256, 0, stream>>>(wih + nw, nw,       AMAX + 3);
  k_absmax<<<256,  256, 0, stream>>>(whh + nw, nw,       AMAX + 4);
  k_absmax<<<2048, 256, 0, stream>>>(fcw,      VOC * DM, AMAX + 5);
  k_finalize<<<1, 8, 0, stream>>>(AMAX, SC);

  k_gather<<<TOK * 64 / 256, 256, 0, stream>>>(x, emb, SC, KEMB);
  k_quant_kbf16<<<nw / 4 / 256,       256, 0, stream>>>(wih, KWIH0, nw / 4,       SC, 1);
  k_quant_kbf16<<<VOC * DM / 4 / 256, 256, 0, stream>>>(fcw, KFC,   VOC * DM / 4, SC, 5);
  k_packrec<<<128, 256, 0, stream>>>(whh,      WL0, SC, 2, 0);
  k_packrec<<<128, 256, 0, stream>>>(wih + nw, WFF, SC, 3, 0);
  k_packrec<<<128, 256, 0, stream>>>(whh + nw, WL1, SC, 4, 0);

  // xgates(layer0) = s0*s1 * (k_emb @ k_wih0^T) + b_ih0 + b_hh0  (integer-exact MFMA)
  dim3 g1(TOK / 128, G4 / 128);
  k_gemm<<<g1, 256, 0, stream>>>(KEMB, KWIH0, XG, TOK, G4, SC + 0, SC + 1, bih, bhh);

  k_rec4<<<128, 512, 0, stream>>>(WL0, WFF, WL1, XG, HX0, HX1, HOUT,
                                  FLAGS, SC, bih, bhh);

  // logits = s_fc * (h @ k_fc^T) + fc_b
  dim3 g2(TOK / 128, VOC / 128);
  k_gemm<<<g2, 256, 0, stream>>>(HOUT, KFC, out, TOK, VOC, SC + 5, SC + 6, fcb, nullptr);
}

// Round 7
// 2713.502 us; speedup vs baseline: 5.8879x; 1.0260x over previous
//
#include <hip/hip_runtime.h>
#include <hip/hip_bf16.h>
#include <stdint.h>

typedef __attribute__((ext_vector_type(8))) short bf16x8;
typedef __attribute__((ext_vector_type(4))) float f32x4;

#define NB   16
#define SEQ  512
#define DM   256
#define G4   1024
#define VOC  32000
#define TOK  (NB*SEQ)          // 8192 tokens

// ---------------- workspace layout (bytes) ----------------
#define OF_SC     0                                  // float[8]
#define OF_AMAX   64                                 // uint[8]
#define OF_FLAG   128                                // int[1024]: F0[8*32], F1[8*32] (128B/flag)
#define OF_KEMB   16384                              // bf16 codes [8192,256]
#define OF_KWIH0  (OF_KEMB  + TOK*DM*2)              // bf16 codes [1024,256]
#define OF_KFC    (OF_KWIH0 + G4*DM*2)               // bf16 codes [32000,256]
#define OF_WL0    (OF_KFC   + VOC*DM*2)              // whh0 A-frags 512KB
#define OF_WFF    (OF_WL0   + 512*64*16)             // wih1 A-frags 512KB
#define OF_WL1    (OF_WFF   + 512*64*16)             // whh1 A-frags 512KB
#define OF_HX0    (OF_WL1   + 512*64*16)             // h0 frag stream [512 t][8 g][2 p][1KB] = 8MB
#define OF_HX1    (OF_HX0   + (size_t)SEQ*16384)     // h1 frag stream, 8MB (write-once!)
#define OF_XG     (OF_HX1   + (size_t)SEQ*16384)     // f32 [8192,1024] layer0 input gates
#define OF_HOUT   (OF_XG    + (size_t)TOK*G4*4)      // bf16 [8192,256] h1 (FC input)

__device__ __forceinline__ unsigned short bf16b(float f) {
  __hip_bfloat16 h = __float2bfloat16(f);
  return *reinterpret_cast<unsigned short*>(&h);
}
__device__ __forceinline__ float bf16f(short u) {
  return __uint_as_float(((unsigned)(unsigned short)u) << 16);
}
__device__ __forceinline__ float quant_k_val(float w, float s) {
  float k = rintf(w / s);                       // round-half-even == jnp.round
  return fminf(fmaxf(k, -8.f), 7.f);
}
__device__ __forceinline__ float sigf(float x) { return 1.f / (1.f + expf(-x)); }

__device__ __forceinline__ void gload_lds16(const void* g, void* l) {
  __builtin_amdgcn_global_load_lds(
      (const __attribute__((address_space(1))) void*)g,
      (__attribute__((address_space(3))) void*)l, 16, 0, 0);
}

// ---- exchange access ----
// Streams are WRITE-ONCE per launch: no consumer cache level can hold a stale
// copy (first fill happens after the flag; inter-dispatch fences cover replays).
// Stores: sc0 sc1 (write through to L3 = the copy cross-XCD consumers fetch).
// Loads: sc0 only (L1-bypass, L2-cacheable fill from L3, ~2-3x lower latency).
__device__ __forceinline__ bf16x8 ld_frag_c(const void* p) {
  bf16x8 r;
  asm volatile("global_load_dwordx4 %0, %1, off sc0" : "=v"(r) : "v"(p));
  return r;
}
__device__ __forceinline__ void st_frag_sys(void* p, bf16x8 v) {
  asm volatile("global_store_dwordx4 %0, %1, off sc0 sc1" :: "v"(p), "v"(v) : "memory");
}
__device__ __forceinline__ void vm_drain() {
  asm volatile("s_waitcnt vmcnt(0)" ::: "memory");
  __builtin_amdgcn_sched_barrier(0);
}
__device__ __forceinline__ void vm_wait16() {
  asm volatile("s_waitcnt vmcnt(16)" ::: "memory");
  __builtin_amdgcn_sched_barrier(0);
}

// relaxed spin (no acquire fence -> no buffer_inv storms)
__device__ __forceinline__ void spin_ge(int* p, int tgt) {
  int it = 0;
  while (__hip_atomic_load(p, __ATOMIC_RELAXED, __HIP_MEMORY_SCOPE_AGENT) < tgt) {
    __builtin_amdgcn_s_sleep(1);
    if (++it > (1 << 15)) break;   // bailout: wrong answer beats hang
  }
}
__device__ __forceinline__ void flag_set(int* p, int v) {
  __hip_atomic_store(p, v, __ATOMIC_RELAXED, __HIP_MEMORY_SCOPE_AGENT);
}

// ---------------- scale computation ----------------
__global__ void k_init(unsigned int* amax, int* flags) {
  if (threadIdx.x < 8) amax[threadIdx.x] = 0u;
  flags[threadIdx.x] = 0;   // 1024 threads
}

__global__ void k_absmax(const float* __restrict__ p, int n, unsigned int* amax) {
  float m = 0.f;
  for (int i = blockIdx.x * blockDim.x + threadIdx.x; i < n; i += gridDim.x * blockDim.x)
    m = fmaxf(m, fabsf(p[i]));
  #pragma unroll
  for (int off = 32; off > 0; off >>= 1)
    m = fmaxf(m, __shfl_down(m, off));
  if ((threadIdx.x & 63) == 0) atomicMax(amax, __float_as_uint(m));
}

__global__ void k_finalize(const unsigned int* __restrict__ amax, float* __restrict__ sc) {
  int i = threadIdx.x;
  if (i < 6)       sc[i] = fmaxf(__uint_as_float(amax[i]) / 7.0f, 1e-8f);
  else if (i == 6) sc[i] = 1.0f;
}

// ---------------- quantize kernels ----------------
__global__ void k_quant_kbf16(const float* __restrict__ src, ushort* __restrict__ dst,
                              int n4, const float* __restrict__ sc, int slot) {
  int i = blockIdx.x * blockDim.x + threadIdx.x;
  if (i >= n4) return;
  const float s = sc[slot];
  float4 w = ((const float4*)src)[i];
  ushort4 o;
  o.x = bf16b(quant_k_val(w.x, s));
  o.y = bf16b(quant_k_val(w.y, s));
  o.z = bf16b(quant_k_val(w.z, s));
  o.w = bf16b(quant_k_val(w.w, s));
  ((ushort4*)dst)[i] = o;
}

__global__ void k_gather(const int* __restrict__ x, const float* __restrict__ emb,
                         const float* __restrict__ sc, ushort* __restrict__ out) {
  int i = blockIdx.x * blockDim.x + threadIdx.x;
  if (i >= TOK * 64) return;
  int tok = i >> 6, d4 = i & 63;
  const float s = sc[0];
  int row = x[tok];
  float4 w = *(const float4*)(emb + (size_t)row * DM + d4 * 4);
  ushort4 o;
  o.x = bf16b(quant_k_val(w.x, s));
  o.y = bf16b(quant_k_val(w.y, s));
  o.z = bf16b(quant_k_val(w.z, s));
  o.w = bf16b(quant_k_val(w.w, s));
  ((ushort4*)out)[i] = o;
}

// pack A-frags (mode 0, validated R3-R6): frag fi = ((g*4+wv)*2+i)*8+c, lane l:
// row = wv*256 + g*32 + i*16 + (l&15), k = c*32 + ((l>>4)&3)*8 + e
__global__ void k_packrec(const float* __restrict__ src, bf16x8* __restrict__ dst,
                          const float* __restrict__ sc, int slot, int mode) {
  int q = blockIdx.x * blockDim.x + threadIdx.x;
  if (q >= 512 * 64) return;
  int l = q & 63, kf = (q >> 6) & 7, i = (q >> 9) & 1, w = (q >> 10) & 3, g = (q >> 12) & 7;
  int row = mode ? (g * 128 + (w * 2 + i) * 16 + (l & 15))
                 : (w * 256 + g * 32 + i * 16 + (l & 15));
  int kb = kf * 32 + ((l >> 4) & 3) * 8;
  const float s = sc[slot];
  const float* p = src + (size_t)row * DM + kb;
  bf16x8 o;
  #pragma unroll
  for (int e = 0; e < 8; ++e) o[e] = (short)bf16b(quant_k_val(p[e], s));
  dst[q] = o;
}

// ---------------- 128x128 MFMA bf16 GEMM (validated R1-R6) ----------------
__global__ __launch_bounds__(256) void k_gemm(
    const ushort* __restrict__ A, const ushort* __restrict__ B,
    float* __restrict__ C, int M, int N,
    const float* __restrict__ s1, const float* __restrict__ s2,
    const float* __restrict__ bias1, const float* __restrict__ bias2)
{
  __shared__ alignas(16) ushort As[128 * 64];
  __shared__ alignas(16) ushort Bs[128 * 64];
  const int tid  = threadIdx.x;
  const int lane = tid & 63;
  const int wid  = tid >> 6;
  const size_t m0 = (size_t)blockIdx.x * 128;
  const size_t n0 = (size_t)blockIdx.y * 128;
  const int wm = (wid >> 1) * 64;
  const int wn = (wid & 1) * 64;
  const int r  = tid >> 3;
  const int c8 = (tid & 7) * 8;

  f32x4 acc[4][4];
  #pragma unroll
  for (int m = 0; m < 4; ++m)
    #pragma unroll
    for (int n = 0; n < 4; ++n) acc[m][n] = (f32x4){0.f, 0.f, 0.f, 0.f};

  for (int k0 = 0; k0 < DM; k0 += 64) {
    #pragma unroll
    for (int i = 0; i < 4; ++i) {
      gload_lds16(A + (m0 + i * 32 + r) * DM + k0 + c8, (char*)As + i * 4096 + wid * 1024);
      gload_lds16(B + (n0 + i * 32 + r) * DM + k0 + c8, (char*)Bs + i * 4096 + wid * 1024);
    }
    __syncthreads();
    #pragma unroll
    for (int kk = 0; kk < 2; ++kk) {
      const int ko = (kk * 32 + ((lane >> 4) << 3)) * 2;
      bf16x8 af[4], bfr[4];
      #pragma unroll
      for (int m = 0; m < 4; ++m)
        af[m] = *(const bf16x8*)((const char*)As + (wm + m * 16 + (lane & 15)) * 128 + ko);
      #pragma unroll
      for (int n = 0; n < 4; ++n)
        bfr[n] = *(const bf16x8*)((const char*)Bs + (wn + n * 16 + (lane & 15)) * 128 + ko);
      #pragma unroll
      for (int m = 0; m < 4; ++m)
        #pragma unroll
        for (int n = 0; n < 4; ++n)
          acc[m][n] = __builtin_amdgcn_mfma_f32_16x16x32_bf16(af[m], bfr[n], acc[m][n], 0, 0, 0);
    }
    __syncthreads();
  }

  const float alpha = s1[0] * s2[0];
  const int cl = lane & 15;
  const int rq = (lane >> 4) * 4;
  #pragma unroll
  for (int n = 0; n < 4; ++n) {
    const size_t col = n0 + wn + n * 16 + cl;
    float badd = 0.f;
    if (bias1) badd += bias1[col];
    if (bias2) badd += bias2[col];
    #pragma unroll
    for (int m = 0; m < 4; ++m) {
      const size_t rowb = m0 + wm + m * 16 + rq;
      #pragma unroll
      for (int q = 0; q < 4; ++q)
        C[(rowb + q) * (size_t)N + col] = acc[m][n][q] * alpha + badd;
    }
  }
}

// ---------------- 2-stage register-resident MFMA LSTM (write-once streams) ----------------
// 16 active blocks (bid%8==0): m=0..7 L0[g], m=8..15 L1[g] (FF merged, K=512).
// 512 threads = 8 waves; wave w: gate = w>>1, row-tile i = w&1.
// h exchange: 2 exact bf16 planes, frag-linear 2KB/block/step, SEQ-deep stream (no reuse):
//   stores sc0sc1 (to L3), loads sc0-only (L2-cacheable). L0 free-runs (no back-pressure).
__global__ __launch_bounds__(512) void k_rec5(
    const bf16x8* __restrict__ WL0, const bf16x8* __restrict__ WFF,
    const bf16x8* __restrict__ WL1, const float* __restrict__ XG,
    ushort* __restrict__ HX0, ushort* __restrict__ HX1,
    ushort* __restrict__ HOUT, int* __restrict__ flags,
    const float* __restrict__ sc,
    const float* __restrict__ bih, const float* __restrict__ bhh)
{
  if (blockIdx.x & 7) return;
  const int m = blockIdx.x >> 3;
  if (m >= 16) return;
  const int role = m >> 3, g = m & 7;
  const int tid = threadIdx.x, lane = tid & 63, w = tid >> 6;
  const int kg = lane >> 4, cb = lane & 15;
  const int r0 = tid & 31, b = tid >> 5;          // act coords: k-row, batch
  const int gw = (g * 4 + (w >> 1)) * 2 + (w & 1);
  __shared__ float Gl[4 * 32 * 17];
  __shared__ alignas(16) ushort hp[1024];          // 2 planes x 64 lanes x 8 halves
  int* F0 = flags;
  int* F1 = flags + 8 * 32;
  const int fl = ((r0 >> 3) << 4) | b;             // frag lane for produced h(k=r0,b)

  if (role == 0) {
    // ================= layer-0 recurrence (free-running) =================
    bf16x8 a[8];
    #pragma unroll
    for (int c = 0; c < 8; ++c) a[c] = WL0[((gw * 8 + c) << 6) + lane];
    const float s2 = sc[2];
    float cc = 0.f;
    for (int t = 0; t < SEQ; ++t) {
      const size_t xb = ((size_t)(b * 512 + t) << 10) + g * 32 + r0;
      float xv0 = XG[xb], xv1 = XG[xb + 256], xv2 = XG[xb + 512], xv3 = XG[xb + 768];
      if (tid < 8) spin_ge(F0 + tid * 32, t);      // peers h0[t-1]; no L1 back-pressure
      __syncthreads();
      f32x4 acc = {0.f, 0.f, 0.f, 0.f};
      if (t > 0) {
        const char* hb = (const char*)HX0 + (size_t)(t - 1) * 16384 + lane * 16;
        bf16x8 bp[16];
        #pragma unroll
        for (int c = 0; c < 8; ++c) {
          bp[2 * c]     = ld_frag_c(hb + c * 2048);
          bp[2 * c + 1] = ld_frag_c(hb + c * 2048 + 1024);
        }
        vm_drain();
        #pragma unroll
        for (int c = 0; c < 8; ++c) {
          acc = __builtin_amdgcn_mfma_f32_16x16x32_bf16(a[c], bp[2 * c],     acc, 0, 0, 0);
          acc = __builtin_amdgcn_mfma_f32_16x16x32_bf16(a[c], bp[2 * c + 1], acc, 0, 0, 0);
        }
      }
      #pragma unroll
      for (int q = 0; q < 4; ++q)
        Gl[((w >> 1) * 32 + (w & 1) * 16 + kg * 4 + q) * 17 + cb] = acc[q];
      __syncthreads();
      {
        float g0 = xv0 + s2 * Gl[(0 * 32 + r0) * 17 + b];
        float g1 = xv1 + s2 * Gl[(1 * 32 + r0) * 17 + b];
        float g2 = xv2 + s2 * Gl[(2 * 32 + r0) * 17 + b];
        float g3 = xv3 + s2 * Gl[(3 * 32 + r0) * 17 + b];
        float i_ = sigf(g0), f_ = sigf(g1), gg = tanhf(g2), o_ = sigf(g3);
        cc = f_ * cc + i_ * gg;
        float h = o_ * tanhf(cc);
        unsigned short p1 = bf16b(h);
        float r1 = h - bf16f((short)p1);
        unsigned short p2 = bf16b(r1);
        hp[fl * 8 + (r0 & 7)]       = p1;
        hp[512 + fl * 8 + (r0 & 7)] = p2;
      }
      __syncthreads();
      if (tid < 128)
        st_frag_sys(HX0 + (size_t)t * 8192 + g * 1024 + tid * 8,
                    *(const bf16x8*)(hp + tid * 8));
      vm_drain();
      __syncthreads();
      if (tid == 0) flag_set(F0 + g * 32, t + 1);
    }
  } else {
    // ====== layer-1 (FF merged): gates = b + s3*wih1.h0[t] + s4*whh1.h1[t-1] ======
    bf16x8 aI[8], aH[8];
    #pragma unroll
    for (int c = 0; c < 8; ++c) {
      aI[c] = WFF[((gw * 8 + c) << 6) + lane];
      aH[c] = WL1[((gw * 8 + c) << 6) + lane];
    }
    const float s3 = sc[3], s4 = sc[4];
    const int jb = G4 + g * 32 + r0;
    const float bb0 = bih[jb]       + bhh[jb];
    const float bb1 = bih[jb + 256] + bhh[jb + 256];
    const float bb2 = bih[jb + 512] + bhh[jb + 512];
    const float bb3 = bih[jb + 768] + bhh[jb + 768];
    float cc = 0.f;
    for (int t = 0; t < SEQ; ++t) {
      // poll BOTH deps up front (L0 runs ahead, F0 wait ~0)
      if (tid < 16) spin_ge((tid < 8) ? F1 + tid * 32 : F0 + (tid - 8) * 32,
                            (tid < 8) ? t : t + 1);
      __syncthreads();
      bf16x8 bpH[16], bpI[16];
      if (t > 0) {
        const char* hb1 = (const char*)HX1 + (size_t)(t - 1) * 16384 + lane * 16;
        #pragma unroll
        for (int c = 0; c < 8; ++c) {
          bpH[2 * c]     = ld_frag_c(hb1 + c * 2048);
          bpH[2 * c + 1] = ld_frag_c(hb1 + c * 2048 + 1024);
        }
      }
      {
        const char* hb0 = (const char*)HX0 + (size_t)t * 16384 + lane * 16;
        #pragma unroll
        for (int c = 0; c < 8; ++c) {
          bpI[2 * c]     = ld_frag_c(hb0 + c * 2048);
          bpI[2 * c + 1] = ld_frag_c(hb0 + c * 2048 + 1024);
        }
      }
      f32x4 accH = {0.f, 0.f, 0.f, 0.f}, accI = {0.f, 0.f, 0.f, 0.f};
      if (t > 0) {
        vm_wait16();                       // H loads (first 16) complete; I still in flight
        #pragma unroll
        for (int c = 0; c < 16; ++c)
          accH = __builtin_amdgcn_mfma_f32_16x16x32_bf16(aH[c >> 1], bpH[c], accH, 0, 0, 0);
      }
      vm_drain();
      #pragma unroll
      for (int c = 0; c < 16; ++c)
        accI = __builtin_amdgcn_mfma_f32_16x16x32_bf16(aI[c >> 1], bpI[c], accI, 0, 0, 0);
      #pragma unroll
      for (int q = 0; q < 4; ++q)
        Gl[((w >> 1) * 32 + (w & 1) * 16 + kg * 4 + q) * 17 + cb] = s3 * accI[q] + s4 * accH[q];
      __syncthreads();
      {
        float g0 = bb0 + Gl[(0 * 32 + r0) * 17 + b];
        float g1 = bb1 + Gl[(1 * 32 + r0) * 17 + b];
        float g2 = bb2 + Gl[(2 * 32 + r0) * 17 + b];
        float g3 = bb3 + Gl[(3 * 32 + r0) * 17 + b];
        float i_ = sigf(g0), f_ = sigf(g1), gg = tanhf(g2), o_ = sigf(g3);
        cc = f_ * cc + i_ * gg;
        float h = o_ * tanhf(cc);
        unsigned short p1 = bf16b(h);
        float r1 = h - bf16f((short)p1);
        unsigned short p2 = bf16b(r1);
        HOUT[((size_t)b * 512 + t) * 256 + g * 32 + r0] = p1;   // plain; next dispatch reads
        hp[fl * 8 + (r0 & 7)]       = p1;
        hp[512 + fl * 8 + (r0 & 7)] = p2;
      }
      __syncthreads();
      if (tid < 128)
        st_frag_sys(HX1 + (size_t)t * 8192 + g * 1024 + tid * 8,
                    *(const bf16x8*)(hp + tid * 8));
      vm_drain();
      __syncthreads();
      if (tid == 0) flag_set(F1 + g * 32, t + 1);
    }
  }
}

// ---------------- launch ----------------
extern "C" void kernel_launch(void* const* d_in, const int* in_sizes, int n_in,
                              void* d_out, int out_size, void* d_ws, size_t ws_size,
                              hipStream_t stream) {
  const int*   x   = (const int*)d_in[0];
  const float* emb = (const float*)d_in[1];
  const float* wih = (const float*)d_in[2];   // [2,1024,256]
  const float* bih = (const float*)d_in[3];   // [2,1024]
  const float* whh = (const float*)d_in[4];
  const float* bhh = (const float*)d_in[5];
  const float* fcw = (const float*)d_in[6];   // [32000,256]
  const float* fcb = (const float*)d_in[7];
  float* out = (float*)d_out;

  char* ws = (char*)d_ws;
  float*        SC    = (float*)(ws + OF_SC);
  unsigned int* AMAX  = (unsigned int*)(ws + OF_AMAX);
  int*          FLAGS = (int*)(ws + OF_FLAG);
  ushort*       KEMB  = (ushort*)(ws + OF_KEMB);
  ushort*       KWIH0 = (ushort*)(ws + OF_KWIH0);
  ushort*       KFC   = (ushort*)(ws + OF_KFC);
  bf16x8*       WL0   = (bf16x8*)(ws + OF_WL0);
  bf16x8*       WFF   = (bf16x8*)(ws + OF_WFF);
  bf16x8*       WL1   = (bf16x8*)(ws + OF_WL1);
  ushort*       HX0   = (ushort*)(ws + OF_HX0);
  ushort*       HX1   = (ushort*)(ws + OF_HX1);
  float*        XG    = (float*)(ws + OF_XG);
  ushort*       HOUT  = (ushort*)(ws + OF_HOUT);

  const int nw = G4 * DM;

  k_init<<<1, 1024, 0, stream>>>(AMAX, FLAGS);
  k_absmax<<<2048, 256, 0, stream>>>(emb,      VOC * DM, AMAX + 0);
  k_absmax<<<256,  256, 0, stream>>>(wih,      nw,       AMAX + 1);
  k_absmax<<<256,  256, 0, stream>>>(whh,      nw,       AMAX + 2);
  k_absmax<<<256,  256, 0, stream>>>(wih + nw, nw,       AMAX + 3);
  k_absmax<<<256,  256, 0, stream>>>(whh + nw, nw,       AMAX + 4);
  k_absmax<<<2048, 256, 0, stream>>>(fcw,      VOC * DM, AMAX + 5);
  k_finalize<<<1, 8, 0, stream>>>(AMAX, SC);

  k_gather<<<TOK * 64 / 256, 256, 0, stream>>>(x, emb, SC, KEMB);
  k_quant_kbf16<<<nw / 4 / 256,       256, 0, stream>>>(wih, KWIH0, nw / 4,       SC, 1);
  k_quant_kbf16<<<VOC * DM / 4 / 256, 256, 0, stream>>>(fcw, KFC,   VOC * DM / 4, SC, 5);
  k_packrec<<<128, 256, 0, stream>>>(whh,      WL0, SC, 2, 0);
  k_packrec<<<128, 256, 0, stream>>>(wih + nw, WFF, SC, 3, 0);
  k_packrec<<<128, 256, 0, stream>>>(whh + nw, WL1, SC, 4, 0);

  // xgates(layer0) = s0*s1 * (k_emb @ k_wih0^T) + b_ih0 + b_hh0  (integer-exact MFMA)
  dim3 g1(TOK / 128, G4 / 128);
  k_gemm<<<g1, 256, 0, stream>>>(KEMB, KWIH0, XG, TOK, G4, SC + 0, SC + 1, bih, bhh);

  k_rec5<<<128, 512, 0, stream>>>(WL0, WFF, WL1, XG, HX0, HX1, HOUT,
                                  FLAGS, SC, bih, bhh);

  // logits = s_fc * (h @ k_fc^T) + fc_b
  dim3 g2(TOK / 128, VOC / 128);
  k_gemm<<<g2, 256, 0, stream>>>(HOUT, KFC, out, TOK, VOC, SC + 5, SC + 6, fcb, nullptr);
}